// Round 10
// baseline (9898.283 us; speedup 1.0000x reference)
//
#include <hip/hip_runtime.h>
#include <math.h>

// LSTM encoder: B=32, S=512, E=512, H=1024, G=4H=4096.
// Round 10: wave-autonomous recurrence. 64 WGs x 512 thr = 512 independent
// waves; wave = (batch-half bt, 4-unit coltile). Per wave per step:
//   poll own 256 flags -> 32 chained MFMA (K=1024, W in 128 VGPRs) ->
//   in-wave shfl transpose -> gates -> write-through h + out -> wave-local
//   vmcnt(0) -> flag. NO __syncthreads, NO LDS in the loop.
// Coherence primitives unchanged (validated r4-r9): write-through atomic
// stores, relaxed atomic-load polls, post-flag first-touch plain loads.

#define B_ 32
#define S_ 512
#define E_ 512
#define H_ 1024
#define G_ 4096
#define NWG 64
#define RTHR 512
#define BH_ (B_ * H_)
#define XGPAD 40

typedef _Float16 f16x8 __attribute__((ext_vector_type(8)));
typedef _Float16 f16x4 __attribute__((ext_vector_type(4)));
typedef float f32x4 __attribute__((ext_vector_type(4)));

__device__ __forceinline__ float sigmoidf_(float x) {
  return 1.0f / (1.0f + __expf(-x));
}
__device__ __forceinline__ float tanhf_(float x) {
  return 1.0f - 2.0f / (__expf(2.0f * x) + 1.0f);
}

// ---- one-time: W f32[K][4096] -> Wt f16[4096][K] (transpose + convert) ----
__global__ __launch_bounds__(256) void wt_kernel(
    const float* __restrict__ W, _Float16* __restrict__ Wt, int K)
{
  __shared__ float Lt[64][65];
  const int c0 = blockIdx.x * 64;
  const int k0 = blockIdx.y * 64;
  const int tid = threadIdx.x;
  const int colL = tid & 63;
  const int rq = tid >> 6;
#pragma unroll 4
  for (int p = 0; p < 16; ++p) {
    int r = p * 4 + rq;
    Lt[colL][r] = W[(size_t)(k0 + r) * G_ + c0 + colL];
  }
  __syncthreads();
  const int col = tid >> 2;
  const int kq = (tid & 3) * 16;
  _Float16 tmp[16];
#pragma unroll
  for (int i = 0; i < 16; ++i) tmp[i] = (_Float16)Lt[col][kq + i];
  *(f16x8*)(Wt + (size_t)(c0 + col) * K + k0 + kq)     = *(f16x8*)&tmp[0];
  *(f16x8*)(Wt + (size_t)(c0 + col) * K + k0 + kq + 8) = *(f16x8*)&tmp[8];
}

// ---- gather embedding rows -> f16 A[chunk*32][512] ----
__global__ __launch_bounds__(128) void gather_a(
    const int* __restrict__ src, const float* __restrict__ emb,
    _Float16* __restrict__ A, int t0)
{
  const int r = blockIdx.x;
  const int t = t0 + (r >> 5), b = r & 31;
  const int vrow = src[b * S_ + t];
  const float4 v = *(const float4*)(emb + (size_t)vrow * E_ + threadIdx.x * 4);
  f16x4 o = { (_Float16)v.x, (_Float16)v.y, (_Float16)v.z, (_Float16)v.w };
  *(f16x4*)(A + (size_t)r * E_ + threadIdx.x * 4) = o;
}

// ---- Phase A: x-gates f16 MFMA GEMM (r9-validated) ----
__global__ __launch_bounds__(256) void xgates_mfma(
    const _Float16* __restrict__ A, const _Float16* __restrict__ Bw,
    const float* __restrict__ bih, const float* __restrict__ bhh,
    _Float16* __restrict__ xg)
{
  __shared__ _Float16 Al[128][XGPAD];
  __shared__ _Float16 Bl[128][XGPAD];
  const int tid = threadIdx.x;
  const int row0 = blockIdx.y * 128;
  const int col0 = blockIdx.x * 128;
  const int wave = tid >> 6, lane = tid & 63;
  const int wm = wave >> 1, wn = wave & 1;
  const int lrow = lane & 15, lhi = lane >> 4;

  float bias[4];
#pragma unroll
  for (int n = 0; n < 4; ++n) {
    int c = col0 + wn * 64 + n * 16 + lrow;
    bias[n] = bih[c] + bhh[c];
  }
  f32x4 acc[4][4];
#pragma unroll
  for (int m = 0; m < 4; ++m)
#pragma unroll
    for (int n = 0; n < 4; ++n)
      acc[m][n] = (f32x4){bias[n], bias[n], bias[n], bias[n]};

  for (int kt = 0; kt < E_ / 32; ++kt) {
#pragma unroll
    for (int p = 0; p < 2; ++p) {
      int cch = tid * 2 + p;
      int rr = cch >> 2, kc = cch & 3;
      *(f16x8*)&Al[rr][kc * 8] =
          *(const f16x8*)(A + (size_t)(row0 + rr) * E_ + kt * 32 + kc * 8);
      *(f16x8*)&Bl[rr][kc * 8] =
          *(const f16x8*)(Bw + (size_t)(col0 + rr) * E_ + kt * 32 + kc * 8);
    }
    __syncthreads();
    f16x8 af[4], bfr[4];
#pragma unroll
    for (int m = 0; m < 4; ++m)
      af[m] = *(const f16x8*)&Al[wm * 64 + m * 16 + lrow][lhi * 8];
#pragma unroll
    for (int n = 0; n < 4; ++n)
      bfr[n] = *(const f16x8*)&Bl[wn * 64 + n * 16 + lrow][lhi * 8];
#pragma unroll
    for (int m = 0; m < 4; ++m)
#pragma unroll
      for (int n = 0; n < 4; ++n)
        acc[m][n] = __builtin_amdgcn_mfma_f32_16x16x32_f16(af[m], bfr[n],
                                                           acc[m][n], 0, 0, 0);
    __syncthreads();
  }
#pragma unroll
  for (int m = 0; m < 4; ++m)
#pragma unroll
    for (int n = 0; n < 4; ++n) {
      const int ccol = col0 + wn * 64 + n * 16 + lrow;
#pragma unroll
      for (int r = 0; r < 4; ++r) {
        const int rrow = row0 + wm * 64 + m * 16 + lhi * 4 + r;
        xg[(size_t)rrow * G_ + ccol] = (_Float16)acc[m][n][r];
      }
    }
}

// ---- Phase R: wave-autonomous recurrent kernel ----
// Wave (wg, bt, ct): owns batches bt*16..+16, units wg*16+ct*4..+4 (16 cols).
// D[16 b][16 c=g*4+j] = h[16][1024] * Wslice[1024][16], K chained in-wave.
__global__ __launch_bounds__(RTHR) void lstm_wave(
    const _Float16* __restrict__ Wt, const _Float16* __restrict__ xg,
    unsigned short* hring, float* cbuf, unsigned* flg,
    float* out, int t0, int nt)
{
  const int wg = blockIdx.x;
  const int tid = threadIdx.x;
  const int wave = tid >> 6;
  const int lane = tid & 63;
  const int lrow = lane & 15, lhi = lane >> 4;
  const int bt = wave >> 2;            // 0..1 batch half
  const int ct = wave & 3;             // 0..3 col tile (4 units)
  // B-frag col c = lrow = g*4+j  ->  global gate col = g*H + unit
  const int gcol = (lrow >> 2) * H_ + wg * 16 + ct * 4 + (lrow & 3);

  // persistent W fragments: 32 x f16x8 = 128 VGPR/lane
  f16x8 bf[32];
#pragma unroll
  for (int s = 0; s < 32; ++s)
    bf[s] = *(const f16x8*)(Wt + (size_t)gcol * H_ + s * 32 + lhi * 8);

  // epilogue item mapping: lane -> (batch-local ebl, unit-local ej)
  const int ej    = lane & 3;
  const int ersel = (lane >> 2) & 3;
  const int ebl   = (lane >> 4) * 4 + ersel;     // 0..15
  const int eb    = bt * 16 + ebl;               // global batch
  const int eu    = wg * 16 + ct * 4 + ej;       // global unit
  const int shbase = (lane & 48) | ej;           // shfl source base

  float cstate = cbuf[(size_t)eb * H_ + eu];

  for (int t = t0; t < t0 + nt; ++t) {
    const int lt = t - t0;
    const _Float16* hrd = (const _Float16*)hring + (size_t)lt * BH_;  // first touch
    unsigned short* hwr = hring + (size_t)((lt == nt - 1) ? 0 : lt + 1) * BH_;

    // ---- poll own batch-half's 256 flags (4 relaxed atomic loads/lane) ----
    {
      const unsigned* fp = flg + (size_t)t * 512 + bt * 256 + lane * 4;
      int guard = 0;
      for (;;) {
        unsigned a0 = __hip_atomic_load(fp + 0, __ATOMIC_RELAXED, __HIP_MEMORY_SCOPE_AGENT);
        unsigned a1 = __hip_atomic_load(fp + 1, __ATOMIC_RELAXED, __HIP_MEMORY_SCOPE_AGENT);
        unsigned a2 = __hip_atomic_load(fp + 2, __ATOMIC_RELAXED, __HIP_MEMORY_SCOPE_AGENT);
        unsigned a3 = __hip_atomic_load(fp + 3, __ATOMIC_RELAXED, __HIP_MEMORY_SCOPE_AGENT);
        if (__all((a0 & a1 & a2 & a3) != 0u)) break;
        __builtin_amdgcn_s_sleep(1);
        if (++guard > (1 << 20)) break;   // bounded: fail loud, never hang
      }
    }

    // ---- xg loads (overlap with h loads below) ----
    const _Float16* xp = xg + ((size_t)lt * B_ + eb) * G_ + eu;
    const float x0 = (float)xp[0];
    const float x1 = (float)xp[H_];
    const float x2 = (float)xp[2 * H_];
    const float x3 = (float)xp[3 * H_];

    // ---- 32 chained MFMA, 2 interleaved accumulators ----
    const _Float16* hp = hrd + (size_t)(bt * 16 + lrow) * H_ + lhi * 8;
    f32x4 acA = {0.f, 0.f, 0.f, 0.f};
    f32x4 acB = {0.f, 0.f, 0.f, 0.f};
#pragma unroll
    for (int sb = 0; sb < 8; ++sb) {
      f16x8 a0 = *(const f16x8*)(hp + (sb * 4 + 0) * 32);
      f16x8 a1 = *(const f16x8*)(hp + (sb * 4 + 1) * 32);
      f16x8 a2 = *(const f16x8*)(hp + (sb * 4 + 2) * 32);
      f16x8 a3 = *(const f16x8*)(hp + (sb * 4 + 3) * 32);
      acA = __builtin_amdgcn_mfma_f32_16x16x32_f16(a0, bf[sb * 4 + 0], acA, 0, 0, 0);
      acB = __builtin_amdgcn_mfma_f32_16x16x32_f16(a1, bf[sb * 4 + 1], acB, 0, 0, 0);
      acA = __builtin_amdgcn_mfma_f32_16x16x32_f16(a2, bf[sb * 4 + 2], acA, 0, 0, 0);
      acB = __builtin_amdgcn_mfma_f32_16x16x32_f16(a3, bf[sb * 4 + 3], acB, 0, 0, 0);
    }
    const float av0 = acA[0] + acB[0];
    const float av1 = acA[1] + acB[1];
    const float av2 = acA[2] + acB[2];
    const float av3 = acA[3] + acB[3];

    // ---- in-wave shfl transpose: gv[g] = D[ebl][g*4+ej] ----
    float gv[4];
#pragma unroll
    for (int g = 0; g < 4; ++g) {
      const int srcl = shbase + g * 4;
      const float t0v = __shfl(av0, srcl);
      const float t1v = __shfl(av1, srcl);
      const float t2v = __shfl(av2, srcl);
      const float t3v = __shfl(av3, srcl);
      gv[g] = (ersel == 0) ? t0v : (ersel == 1) ? t1v : (ersel == 2) ? t2v : t3v;
    }

    // ---- gates + state update ----
    const float ig = sigmoidf_(x0 + gv[0]);
    const float fg = sigmoidf_(x1 + gv[1]);
    const float gg = tanhf_(x2 + gv[2]);
    const float og = sigmoidf_(x3 + gv[3]);
    cstate = fg * cstate + ig * gg;
    const float hval = og * tanhf_(cstate);

    out[((size_t)eb * S_ + t) * H_ + eu] = hval;        // f32, pre-quantization
    const _Float16 hf = (_Float16)hval;
    unsigned short hb;
    __builtin_memcpy(&hb, &hf, 2);
    __hip_atomic_store(hwr + (size_t)eb * H_ + eu, hb,  // write-through
                       __ATOMIC_RELAXED, __HIP_MEMORY_SCOPE_AGENT);

    asm volatile("s_waitcnt vmcnt(0)" ::: "memory");    // wave-local drain
    if (lane == 0)
      __hip_atomic_store(flg + (size_t)(t + 1) * 512 + bt * 256 + wg * 4 + ct,
                         1u, __ATOMIC_RELAXED, __HIP_MEMORY_SCOPE_AGENT);
  }

  cbuf[(size_t)eb * H_ + eu] = cstate;
}

// ---------------- host ----------------
extern "C" void kernel_launch(void* const* d_in, const int* in_sizes, int n_in,
                              void* d_out, int out_size, void* d_ws, size_t ws_size,
                              hipStream_t stream) {
  const int*   src = (const int*)d_in[0];
  const float* emb = (const float*)d_in[1];
  const float* Wih = (const float*)d_in[2];
  const float* Whh = (const float*)d_in[3];
  const float* bih = (const float*)d_in[4];
  const float* bhh = (const float*)d_in[5];
  float* out = (float*)d_out;

  // ws: [cbuf 128K][flg (S+1)*512*4][Wt 8M][Wt2 4M][hring][Af16][xg f16]
  char* ws = (char*)d_ws;
  float*    cbuf = (float*)ws;                          // 131072
  unsigned* flg  = (unsigned*)(ws + 131072);            // 513*512*4 = 1050624
  const size_t stateBytes = 131072 + 1050624;           // 1181696
  _Float16* Wt  = (_Float16*)(ws + stateBytes);                 // 8 MB
  _Float16* Wt2 = (_Float16*)(ws + stateBytes + 8388608);       // 4 MB
  const size_t fixedBytes = stateBytes + 8388608 + 4194304;

  int chunk = 0;
  const int cand[4] = {512, 256, 128, 64};
  for (int ci = 0; ci < 4; ++ci) {
    size_t need = fixedBytes + (size_t)(cand[ci] + 1) * (BH_ * 2)   // hring
                  + (size_t)cand[ci] * B_ * E_ * 2                  // Af16
                  + (size_t)cand[ci] * B_ * G_ * 2;                 // xg f16
    if (need <= ws_size) { chunk = cand[ci]; break; }
  }
  if (chunk == 0) return;  // fail loud

  unsigned short* hring = (unsigned short*)(ws + fixedBytes);
  _Float16* Af16 = (_Float16*)(ws + fixedBytes + (size_t)(chunk + 1) * (BH_ * 2));
  _Float16* xg   = (_Float16*)(ws + fixedBytes + (size_t)(chunk + 1) * (BH_ * 2)
                               + (size_t)chunk * B_ * E_ * 2);

  (void)hipMemsetAsync(ws, 0, stateBytes, stream);   // c0 = 0, all flags = 0
  (void)hipMemsetAsync(flg, 1, 2048, stream);        // seed flags[t=0][both halves]
  (void)hipMemsetAsync(hring, 0, BH_ * 2, stream);   // h0 = 0 (ring slot 0)

  int K1 = H_, K2 = E_;
  wt_kernel<<<dim3(64, 16), 256, 0, stream>>>(Whh, Wt, K1);
  wt_kernel<<<dim3(64, 8), 256, 0, stream>>>(Wih, Wt2, K2);

  for (int t0 = 0; t0 < S_; t0 += chunk) {
    gather_a<<<dim3(chunk * B_), 128, 0, stream>>>(src, emb, Af16, t0);
    xgates_mfma<<<dim3(G_ / 128, chunk * B_ / 128), 256, 0, stream>>>(
        Af16, Wt2, bih, bhh, xg);

    int nt = chunk;
    void* args[] = {(void*)&Wt, (void*)&xg, (void*)&hring, (void*)&cbuf,
                    (void*)&flg, (void*)&out, (void*)&t0, (void*)&nt};
    (void)hipLaunchCooperativeKernel((void*)lstm_wave, dim3(NWG), dim3(RTHR),
                                     args, 0u, stream);
  }
}

// Round 11
// 7791.334 us; speedup vs baseline: 1.2704x; 1.2704x over previous
//
#include <hip/hip_runtime.h>
#include <math.h>

// LSTM encoder: B=32, S=512, E=512, H=1024, G=4H=4096.
// Round 11 = round 10's wave-autonomous structure with its preconditions
// actually enforced:
//   - __launch_bounds__(512, 2): VGPR cap 256 -> bf[32] (128 VGPR) stays in
//     registers (r10 failure: default cap -> scratch, VGPR_Count=84, 19us/step)
//   - LDS relay: waves 0/4 poll MALL flags, others spin on a shared tag
//   - xg loads hoisted above the gate; out store moved after flag publish
// Coherence primitives unchanged (validated r4-r9).

#define B_ 32
#define S_ 512
#define E_ 512
#define H_ 1024
#define G_ 4096
#define NWG 64
#define RTHR 512
#define BH_ (B_ * H_)
#define XGPAD 40

typedef _Float16 f16x8 __attribute__((ext_vector_type(8)));
typedef _Float16 f16x4 __attribute__((ext_vector_type(4)));
typedef float f32x4 __attribute__((ext_vector_type(4)));

__device__ __forceinline__ float sigmoidf_(float x) {
  return 1.0f / (1.0f + __expf(-x));
}
__device__ __forceinline__ float tanhf_(float x) {
  return 1.0f - 2.0f / (__expf(2.0f * x) + 1.0f);
}

// ---- one-time: W f32[K][4096] -> Wt f16[4096][K] (transpose + convert) ----
__global__ __launch_bounds__(256) void wt_kernel(
    const float* __restrict__ W, _Float16* __restrict__ Wt, int K)
{
  __shared__ float Lt[64][65];
  const int c0 = blockIdx.x * 64;
  const int k0 = blockIdx.y * 64;
  const int tid = threadIdx.x;
  const int colL = tid & 63;
  const int rq = tid >> 6;
#pragma unroll 4
  for (int p = 0; p < 16; ++p) {
    int r = p * 4 + rq;
    Lt[colL][r] = W[(size_t)(k0 + r) * G_ + c0 + colL];
  }
  __syncthreads();
  const int col = tid >> 2;
  const int kq = (tid & 3) * 16;
  _Float16 tmp[16];
#pragma unroll
  for (int i = 0; i < 16; ++i) tmp[i] = (_Float16)Lt[col][kq + i];
  *(f16x8*)(Wt + (size_t)(c0 + col) * K + k0 + kq)     = *(f16x8*)&tmp[0];
  *(f16x8*)(Wt + (size_t)(c0 + col) * K + k0 + kq + 8) = *(f16x8*)&tmp[8];
}

// ---- gather embedding rows -> f16 A[chunk*32][512] ----
__global__ __launch_bounds__(128) void gather_a(
    const int* __restrict__ src, const float* __restrict__ emb,
    _Float16* __restrict__ A, int t0)
{
  const int r = blockIdx.x;
  const int t = t0 + (r >> 5), b = r & 31;
  const int vrow = src[b * S_ + t];
  const float4 v = *(const float4*)(emb + (size_t)vrow * E_ + threadIdx.x * 4);
  f16x4 o = { (_Float16)v.x, (_Float16)v.y, (_Float16)v.z, (_Float16)v.w };
  *(f16x4*)(A + (size_t)r * E_ + threadIdx.x * 4) = o;
}

// ---- Phase A: x-gates f16 MFMA GEMM (r9-validated) ----
__global__ __launch_bounds__(256) void xgates_mfma(
    const _Float16* __restrict__ A, const _Float16* __restrict__ Bw,
    const float* __restrict__ bih, const float* __restrict__ bhh,
    _Float16* __restrict__ xg)
{
  __shared__ _Float16 Al[128][XGPAD];
  __shared__ _Float16 Bl[128][XGPAD];
  const int tid = threadIdx.x;
  const int row0 = blockIdx.y * 128;
  const int col0 = blockIdx.x * 128;
  const int wave = tid >> 6, lane = tid & 63;
  const int wm = wave >> 1, wn = wave & 1;
  const int lrow = lane & 15, lhi = lane >> 4;

  float bias[4];
#pragma unroll
  for (int n = 0; n < 4; ++n) {
    int c = col0 + wn * 64 + n * 16 + lrow;
    bias[n] = bih[c] + bhh[c];
  }
  f32x4 acc[4][4];
#pragma unroll
  for (int m = 0; m < 4; ++m)
#pragma unroll
    for (int n = 0; n < 4; ++n)
      acc[m][n] = (f32x4){bias[n], bias[n], bias[n], bias[n]};

  for (int kt = 0; kt < E_ / 32; ++kt) {
#pragma unroll
    for (int p = 0; p < 2; ++p) {
      int cch = tid * 2 + p;
      int rr = cch >> 2, kc = cch & 3;
      *(f16x8*)&Al[rr][kc * 8] =
          *(const f16x8*)(A + (size_t)(row0 + rr) * E_ + kt * 32 + kc * 8);
      *(f16x8*)&Bl[rr][kc * 8] =
          *(const f16x8*)(Bw + (size_t)(col0 + rr) * E_ + kt * 32 + kc * 8);
    }
    __syncthreads();
    f16x8 af[4], bfr[4];
#pragma unroll
    for (int m = 0; m < 4; ++m)
      af[m] = *(const f16x8*)&Al[wm * 64 + m * 16 + lrow][lhi * 8];
#pragma unroll
    for (int n = 0; n < 4; ++n)
      bfr[n] = *(const f16x8*)&Bl[wn * 64 + n * 16 + lrow][lhi * 8];
#pragma unroll
    for (int m = 0; m < 4; ++m)
#pragma unroll
      for (int n = 0; n < 4; ++n)
        acc[m][n] = __builtin_amdgcn_mfma_f32_16x16x32_f16(af[m], bfr[n],
                                                           acc[m][n], 0, 0, 0);
    __syncthreads();
  }
#pragma unroll
  for (int m = 0; m < 4; ++m)
#pragma unroll
    for (int n = 0; n < 4; ++n) {
      const int ccol = col0 + wn * 64 + n * 16 + lrow;
#pragma unroll
      for (int r = 0; r < 4; ++r) {
        const int rrow = row0 + wm * 64 + m * 16 + lhi * 4 + r;
        xg[(size_t)rrow * G_ + ccol] = (_Float16)acc[m][n][r];
      }
    }
}

// ---- Phase R: wave-autonomous recurrent kernel ----
// Wave (wg, bt, ct): owns batches bt*16..+16, units wg*16+ct*4..+4 (16 cols).
// D[16 b][16 c=g*4+j] = h[16][1024] * Wslice[1024][16], K chained in-wave.
__global__ __launch_bounds__(RTHR, 2) void lstm_wave(
    const _Float16* __restrict__ Wt, const _Float16* __restrict__ xg,
    unsigned short* hring, float* cbuf, unsigned* flg,
    float* out, int t0, int nt)
{
  __shared__ int relay[2];             // step tag per batch-half

  const int wg = blockIdx.x;
  const int tid = threadIdx.x;
  const int wave = tid >> 6;
  const int lane = tid & 63;
  const int lrow = lane & 15, lhi = lane >> 4;
  const int bt = wave >> 2;            // 0..1 batch half
  const int ct = wave & 3;             // 0..3 col tile (4 units)
  const int gcol = (lrow >> 2) * H_ + wg * 16 + ct * 4 + (lrow & 3);

  if (tid == 0) { relay[0] = -1; relay[1] = -1; }
  __syncthreads();   // one-time init

  // persistent W fragments: 32 x f16x8 = 128 VGPR/lane (cap 256 via LB(512,2))
  f16x8 bf[32];
#pragma unroll
  for (int s = 0; s < 32; ++s)
    bf[s] = *(const f16x8*)(Wt + (size_t)gcol * H_ + s * 32 + lhi * 8);

  // epilogue item mapping: lane -> (batch-local ebl, unit-local ej)
  const int ej    = lane & 3;
  const int ersel = (lane >> 2) & 3;
  const int ebl   = (lane >> 4) * 4 + ersel;     // 0..15
  const int eb    = bt * 16 + ebl;               // global batch
  const int eu    = wg * 16 + ct * 4 + ej;       // global unit
  const int shbase = (lane & 48) | ej;           // shfl source base

  float cstate = cbuf[(size_t)eb * H_ + eu];

  for (int t = t0; t < t0 + nt; ++t) {
    const int lt = t - t0;
    const _Float16* hrd = (const _Float16*)hring + (size_t)lt * BH_;  // first touch
    unsigned short* hwr = hring + (size_t)((lt == nt - 1) ? 0 : lt + 1) * BH_;

    // ---- xg loads: independent of h, issue before the gate ----
    const _Float16* xp = xg + ((size_t)lt * B_ + eb) * G_ + eu;
    const float x0 = (float)xp[0];
    const float x1 = (float)xp[H_];
    const float x2 = (float)xp[2 * H_];
    const float x3 = (float)xp[3 * H_];

    // ---- gate: waves 0/4 poll MALL flags; others spin on LDS relay ----
    if ((wave & 3) == 0) {
      const unsigned* fp = flg + (size_t)t * 512 + bt * 256 + lane * 4;
      int guard = 0;
      for (;;) {
        unsigned a0 = __hip_atomic_load(fp + 0, __ATOMIC_RELAXED, __HIP_MEMORY_SCOPE_AGENT);
        unsigned a1 = __hip_atomic_load(fp + 1, __ATOMIC_RELAXED, __HIP_MEMORY_SCOPE_AGENT);
        unsigned a2 = __hip_atomic_load(fp + 2, __ATOMIC_RELAXED, __HIP_MEMORY_SCOPE_AGENT);
        unsigned a3 = __hip_atomic_load(fp + 3, __ATOMIC_RELAXED, __HIP_MEMORY_SCOPE_AGENT);
        if (__all((a0 & a1 & a2 & a3) != 0u)) break;
        __builtin_amdgcn_s_sleep(1);
        if (++guard > (1 << 20)) break;   // bounded: fail loud, never hang
      }
      __hip_atomic_store(&relay[bt], t, __ATOMIC_RELAXED,
                         __HIP_MEMORY_SCOPE_WORKGROUP);
    } else {
      int guard = 0;
      while (__hip_atomic_load(&relay[bt], __ATOMIC_RELAXED,
                               __HIP_MEMORY_SCOPE_WORKGROUP) < t) {
        __builtin_amdgcn_s_sleep(1);
        if (++guard > (1 << 20)) break;   // bounded: fail loud, never hang
      }
    }
    asm volatile("" ::: "memory");   // compiler fence: no h-load hoisting

    // ---- 32 chained MFMA, 2 interleaved accumulators ----
    const _Float16* hp = hrd + (size_t)(bt * 16 + lrow) * H_ + lhi * 8;
    f32x4 acA = {0.f, 0.f, 0.f, 0.f};
    f32x4 acB = {0.f, 0.f, 0.f, 0.f};
#pragma unroll
    for (int sb = 0; sb < 8; ++sb) {
      f16x8 a0 = *(const f16x8*)(hp + (sb * 4 + 0) * 32);
      f16x8 a1 = *(const f16x8*)(hp + (sb * 4 + 1) * 32);
      f16x8 a2 = *(const f16x8*)(hp + (sb * 4 + 2) * 32);
      f16x8 a3 = *(const f16x8*)(hp + (sb * 4 + 3) * 32);
      acA = __builtin_amdgcn_mfma_f32_16x16x32_f16(a0, bf[sb * 4 + 0], acA, 0, 0, 0);
      acB = __builtin_amdgcn_mfma_f32_16x16x32_f16(a1, bf[sb * 4 + 1], acB, 0, 0, 0);
      acA = __builtin_amdgcn_mfma_f32_16x16x32_f16(a2, bf[sb * 4 + 2], acA, 0, 0, 0);
      acB = __builtin_amdgcn_mfma_f32_16x16x32_f16(a3, bf[sb * 4 + 3], acB, 0, 0, 0);
    }
    const float av0 = acA[0] + acB[0];
    const float av1 = acA[1] + acB[1];
    const float av2 = acA[2] + acB[2];
    const float av3 = acA[3] + acB[3];

    // ---- in-wave shfl transpose: gv[g] = D[ebl][g*4+ej] ----
    float gv[4];
#pragma unroll
    for (int g = 0; g < 4; ++g) {
      const int srcl = shbase + g * 4;
      const float t0v = __shfl(av0, srcl);
      const float t1v = __shfl(av1, srcl);
      const float t2v = __shfl(av2, srcl);
      const float t3v = __shfl(av3, srcl);
      gv[g] = (ersel == 0) ? t0v : (ersel == 1) ? t1v : (ersel == 2) ? t2v : t3v;
    }

    // ---- gates + state update ----
    const float ig = sigmoidf_(x0 + gv[0]);
    const float fg = sigmoidf_(x1 + gv[1]);
    const float gg = tanhf_(x2 + gv[2]);
    const float og = sigmoidf_(x3 + gv[3]);
    cstate = fg * cstate + ig * gg;
    const float hval = og * tanhf_(cstate);

    const _Float16 hf = (_Float16)hval;
    unsigned short hb;
    __builtin_memcpy(&hb, &hf, 2);
    __hip_atomic_store(hwr + (size_t)eb * H_ + eu, hb,  // write-through
                       __ATOMIC_RELAXED, __HIP_MEMORY_SCOPE_AGENT);

    asm volatile("s_waitcnt vmcnt(0)" ::: "memory");    // wave-local drain (h only)
    if (lane == 0)
      __hip_atomic_store(flg + (size_t)(t + 1) * 512 + bt * 256 + wg * 4 + ct,
                         1u, __ATOMIC_RELAXED, __HIP_MEMORY_SCOPE_AGENT);

    out[((size_t)eb * S_ + t) * H_ + eu] = hval;        // off the critical path
  }

  cbuf[(size_t)eb * H_ + eu] = cstate;
}

// ---------------- host ----------------
extern "C" void kernel_launch(void* const* d_in, const int* in_sizes, int n_in,
                              void* d_out, int out_size, void* d_ws, size_t ws_size,
                              hipStream_t stream) {
  const int*   src = (const int*)d_in[0];
  const float* emb = (const float*)d_in[1];
  const float* Wih = (const float*)d_in[2];
  const float* Whh = (const float*)d_in[3];
  const float* bih = (const float*)d_in[4];
  const float* bhh = (const float*)d_in[5];
  float* out = (float*)d_out;

  // ws: [cbuf 128K][flg (S+1)*512*4][Wt 8M][Wt2 4M][hring][Af16][xg f16]
  char* ws = (char*)d_ws;
  float*    cbuf = (float*)ws;                          // 131072
  unsigned* flg  = (unsigned*)(ws + 131072);            // 513*512*4 = 1050624
  const size_t stateBytes = 131072 + 1050624;           // 1181696
  _Float16* Wt  = (_Float16*)(ws + stateBytes);                 // 8 MB
  _Float16* Wt2 = (_Float16*)(ws + stateBytes + 8388608);       // 4 MB
  const size_t fixedBytes = stateBytes + 8388608 + 4194304;

  int chunk = 0;
  const int cand[4] = {512, 256, 128, 64};
  for (int ci = 0; ci < 4; ++ci) {
    size_t need = fixedBytes + (size_t)(cand[ci] + 1) * (BH_ * 2)   // hring
                  + (size_t)cand[ci] * B_ * E_ * 2                  // Af16
                  + (size_t)cand[ci] * B_ * G_ * 2;                 // xg f16
    if (need <= ws_size) { chunk = cand[ci]; break; }
  }
  if (chunk == 0) return;  // fail loud

  unsigned short* hring = (unsigned short*)(ws + fixedBytes);
  _Float16* Af16 = (_Float16*)(ws + fixedBytes + (size_t)(chunk + 1) * (BH_ * 2));
  _Float16* xg   = (_Float16*)(ws + fixedBytes + (size_t)(chunk + 1) * (BH_ * 2)
                               + (size_t)chunk * B_ * E_ * 2);

  (void)hipMemsetAsync(ws, 0, stateBytes, stream);   // c0 = 0, all flags = 0
  (void)hipMemsetAsync(flg, 1, 2048, stream);        // seed flags[t=0][both halves]
  (void)hipMemsetAsync(hring, 0, BH_ * 2, stream);   // h0 = 0 (ring slot 0)

  int K1 = H_, K2 = E_;
  wt_kernel<<<dim3(64, 16), 256, 0, stream>>>(Whh, Wt, K1);
  wt_kernel<<<dim3(64, 8), 256, 0, stream>>>(Wih, Wt2, K2);

  for (int t0 = 0; t0 < S_; t0 += chunk) {
    gather_a<<<dim3(chunk * B_), 128, 0, stream>>>(src, emb, Af16, t0);
    xgates_mfma<<<dim3(G_ / 128, chunk * B_ / 128), 256, 0, stream>>>(
        Af16, Wt2, bih, bhh, xg);

    int nt = chunk;
    void* args[] = {(void*)&Wt, (void*)&xg, (void*)&hring, (void*)&cbuf,
                    (void*)&flg, (void*)&out, (void*)&t0, (void*)&nt};
    (void)hipLaunchCooperativeKernel((void*)lstm_wave, dim3(NWG), dim3(RTHR),
                                     args, 0u, stream);
  }
}

// Round 12
// 6109.509 us; speedup vs baseline: 1.6201x; 1.2753x over previous
//
#include <hip/hip_runtime.h>
#include <math.h>

// LSTM encoder: B=32, S=512, E=512, H=1024, G=4H=4096.
// Round 12: wave-chained recurrence with W in 32 NAMED f16x8 registers
// (r10/r11's bf[32] array was SROA-demoted to scratch -> VGPR_Count 84,
// scratch refetch 215MB/dispatch; named variables force promotion).
// Sync: r9-validated WG-flag scheme — all waves poll 64 flags (1 load/lane),
// one __syncthreads drains h-stores, tid0 publishes. No LDS in the loop.
// Math (chained MFMA + shfl transpose) is r10/r11-validated (absmax 0.0039).

#define B_ 32
#define S_ 512
#define E_ 512
#define H_ 1024
#define G_ 4096
#define NWG 64
#define RTHR 512
#define BH_ (B_ * H_)
#define XGPAD 40

typedef _Float16 f16x8 __attribute__((ext_vector_type(8)));
typedef _Float16 f16x4 __attribute__((ext_vector_type(4)));
typedef float f32x4 __attribute__((ext_vector_type(4)));

__device__ __forceinline__ float sigmoidf_(float x) {
  return 1.0f / (1.0f + __expf(-x));
}
__device__ __forceinline__ float tanhf_(float x) {
  return 1.0f - 2.0f / (__expf(2.0f * x) + 1.0f);
}

// ---- one-time: W f32[K][4096] -> Wt f16[4096][K] (transpose + convert) ----
__global__ __launch_bounds__(256) void wt_kernel(
    const float* __restrict__ W, _Float16* __restrict__ Wt, int K)
{
  __shared__ float Lt[64][65];
  const int c0 = blockIdx.x * 64;
  const int k0 = blockIdx.y * 64;
  const int tid = threadIdx.x;
  const int colL = tid & 63;
  const int rq = tid >> 6;
#pragma unroll 4
  for (int p = 0; p < 16; ++p) {
    int r = p * 4 + rq;
    Lt[colL][r] = W[(size_t)(k0 + r) * G_ + c0 + colL];
  }
  __syncthreads();
  const int col = tid >> 2;
  const int kq = (tid & 3) * 16;
  _Float16 tmp[16];
#pragma unroll
  for (int i = 0; i < 16; ++i) tmp[i] = (_Float16)Lt[col][kq + i];
  *(f16x8*)(Wt + (size_t)(c0 + col) * K + k0 + kq)     = *(f16x8*)&tmp[0];
  *(f16x8*)(Wt + (size_t)(c0 + col) * K + k0 + kq + 8) = *(f16x8*)&tmp[8];
}

// ---- gather embedding rows -> f16 A[chunk*32][512] ----
__global__ __launch_bounds__(128) void gather_a(
    const int* __restrict__ src, const float* __restrict__ emb,
    _Float16* __restrict__ A, int t0)
{
  const int r = blockIdx.x;
  const int t = t0 + (r >> 5), b = r & 31;
  const int vrow = src[b * S_ + t];
  const float4 v = *(const float4*)(emb + (size_t)vrow * E_ + threadIdx.x * 4);
  f16x4 o = { (_Float16)v.x, (_Float16)v.y, (_Float16)v.z, (_Float16)v.w };
  *(f16x4*)(A + (size_t)r * E_ + threadIdx.x * 4) = o;
}

// ---- Phase A: x-gates f16 MFMA GEMM (r9-validated) ----
__global__ __launch_bounds__(256) void xgates_mfma(
    const _Float16* __restrict__ A, const _Float16* __restrict__ Bw,
    const float* __restrict__ bih, const float* __restrict__ bhh,
    _Float16* __restrict__ xg)
{
  __shared__ _Float16 Al[128][XGPAD];
  __shared__ _Float16 Bl[128][XGPAD];
  const int tid = threadIdx.x;
  const int row0 = blockIdx.y * 128;
  const int col0 = blockIdx.x * 128;
  const int wave = tid >> 6, lane = tid & 63;
  const int wm = wave >> 1, wn = wave & 1;
  const int lrow = lane & 15, lhi = lane >> 4;

  float bias[4];
#pragma unroll
  for (int n = 0; n < 4; ++n) {
    int c = col0 + wn * 64 + n * 16 + lrow;
    bias[n] = bih[c] + bhh[c];
  }
  f32x4 acc[4][4];
#pragma unroll
  for (int m = 0; m < 4; ++m)
#pragma unroll
    for (int n = 0; n < 4; ++n)
      acc[m][n] = (f32x4){bias[n], bias[n], bias[n], bias[n]};

  for (int kt = 0; kt < E_ / 32; ++kt) {
#pragma unroll
    for (int p = 0; p < 2; ++p) {
      int cch = tid * 2 + p;
      int rr = cch >> 2, kc = cch & 3;
      *(f16x8*)&Al[rr][kc * 8] =
          *(const f16x8*)(A + (size_t)(row0 + rr) * E_ + kt * 32 + kc * 8);
      *(f16x8*)&Bl[rr][kc * 8] =
          *(const f16x8*)(Bw + (size_t)(col0 + rr) * E_ + kt * 32 + kc * 8);
    }
    __syncthreads();
    f16x8 af[4], bfr[4];
#pragma unroll
    for (int m = 0; m < 4; ++m)
      af[m] = *(const f16x8*)&Al[wm * 64 + m * 16 + lrow][lhi * 8];
#pragma unroll
    for (int n = 0; n < 4; ++n)
      bfr[n] = *(const f16x8*)&Bl[wn * 64 + n * 16 + lrow][lhi * 8];
#pragma unroll
    for (int m = 0; m < 4; ++m)
#pragma unroll
      for (int n = 0; n < 4; ++n)
        acc[m][n] = __builtin_amdgcn_mfma_f32_16x16x32_f16(af[m], bfr[n],
                                                           acc[m][n], 0, 0, 0);
    __syncthreads();
  }
#pragma unroll
  for (int m = 0; m < 4; ++m)
#pragma unroll
    for (int n = 0; n < 4; ++n) {
      const int ccol = col0 + wn * 64 + n * 16 + lrow;
#pragma unroll
      for (int r = 0; r < 4; ++r) {
        const int rrow = row0 + wm * 64 + m * 16 + lhi * 4 + r;
        xg[(size_t)rrow * G_ + ccol] = (_Float16)acc[m][n][r];
      }
    }
}

// ---- Phase R: wave-chained recurrent kernel, W in named registers ----
// Wave (wg, bt, ct): batches bt*16..+16, units wg*16+ct*4..+4 (16 gate cols).
// D[16 b][16 c=g*4+j] = h[16][1024] * Wslice[1024][16], K=1024 chained.
#define BFDECL(i) const f16x8 bf_##i = *(const f16x8*)(wp + (i) * 32);
#define LSTEP(i, ac) { const f16x8 av_##i = *(const f16x8*)(hp + (i) * 32); \
    ac = __builtin_amdgcn_mfma_f32_16x16x32_f16(av_##i, bf_##i, ac, 0, 0, 0); }

__global__ __launch_bounds__(RTHR, 2) void lstm_wave(
    const _Float16* __restrict__ Wt, const _Float16* __restrict__ xg,
    unsigned short* hring, float* cbuf, unsigned* flg,
    float* out, int t0, int nt)
{
  const int wg = blockIdx.x;
  const int tid = threadIdx.x;
  const int wave = tid >> 6;
  const int lane = tid & 63;
  const int lrow = lane & 15, lhi = lane >> 4;
  const int bt = wave >> 2;            // 0..1 batch half
  const int ct = wave & 3;             // 0..3 col tile (4 units)
  const int gcol = (lrow >> 2) * H_ + wg * 16 + ct * 4 + (lrow & 3);

  // 32 NAMED W fragments: 128 VGPR/lane, immune to SROA array demotion
  const _Float16* wp = Wt + (size_t)gcol * H_ + lhi * 8;
  BFDECL(0)  BFDECL(1)  BFDECL(2)  BFDECL(3)
  BFDECL(4)  BFDECL(5)  BFDECL(6)  BFDECL(7)
  BFDECL(8)  BFDECL(9)  BFDECL(10) BFDECL(11)
  BFDECL(12) BFDECL(13) BFDECL(14) BFDECL(15)
  BFDECL(16) BFDECL(17) BFDECL(18) BFDECL(19)
  BFDECL(20) BFDECL(21) BFDECL(22) BFDECL(23)
  BFDECL(24) BFDECL(25) BFDECL(26) BFDECL(27)
  BFDECL(28) BFDECL(29) BFDECL(30) BFDECL(31)

  // epilogue item mapping: lane -> (batch-local ebl, unit-local ej)
  const int ej    = lane & 3;
  const int ersel = (lane >> 2) & 3;
  const int ebl   = (lane >> 4) * 4 + ersel;     // 0..15
  const int eb    = bt * 16 + ebl;               // global batch
  const int eu    = wg * 16 + ct * 4 + ej;       // global unit
  const int shbase = (lane & 48) | ej;           // shfl source base

  float cstate = cbuf[(size_t)eb * H_ + eu];

  for (int t = t0; t < t0 + nt; ++t) {
    const int lt = t - t0;
    const _Float16* hrd = (const _Float16*)hring + (size_t)lt * BH_;  // first touch
    unsigned short* hwr = hring + (size_t)((lt == nt - 1) ? 0 : lt + 1) * BH_;

    // xg loads: independent of h, issue before the gate
    const _Float16* xp = xg + ((size_t)lt * B_ + eb) * G_ + eu;
    const float x0 = (float)xp[0];
    const float x1 = (float)xp[H_];
    const float x2 = (float)xp[2 * H_];
    const float x3 = (float)xp[3 * H_];

    // ---- gate: every wave polls the 64 WG-flags (1 load/lane) ----
    {
      const unsigned* fp = flg + (size_t)t * 64 + lane;
      int guard = 0;
      for (;;) {
        unsigned v = __hip_atomic_load(fp, __ATOMIC_RELAXED,
                                       __HIP_MEMORY_SCOPE_AGENT);
        if (__all(v != 0u)) break;
        __builtin_amdgcn_s_sleep(1);
        if (++guard > (1 << 20)) break;   // bounded: fail loud, never hang
      }
    }
    asm volatile("" ::: "memory");   // no h-load hoisting above the gate

    // ---- 32 chained MFMA, 2 interleaved accumulators ----
    const _Float16* hp = hrd + (size_t)(bt * 16 + lrow) * H_ + lhi * 8;
    f32x4 acA = {0.f, 0.f, 0.f, 0.f};
    f32x4 acB = {0.f, 0.f, 0.f, 0.f};
    LSTEP(0, acA)  LSTEP(1, acB)  LSTEP(2, acA)  LSTEP(3, acB)
    LSTEP(4, acA)  LSTEP(5, acB)  LSTEP(6, acA)  LSTEP(7, acB)
    LSTEP(8, acA)  LSTEP(9, acB)  LSTEP(10, acA) LSTEP(11, acB)
    LSTEP(12, acA) LSTEP(13, acB) LSTEP(14, acA) LSTEP(15, acB)
    LSTEP(16, acA) LSTEP(17, acB) LSTEP(18, acA) LSTEP(19, acB)
    LSTEP(20, acA) LSTEP(21, acB) LSTEP(22, acA) LSTEP(23, acB)
    LSTEP(24, acA) LSTEP(25, acB) LSTEP(26, acA) LSTEP(27, acB)
    LSTEP(28, acA) LSTEP(29, acB) LSTEP(30, acA) LSTEP(31, acB)
    const float av0 = acA[0] + acB[0];
    const float av1 = acA[1] + acB[1];
    const float av2 = acA[2] + acB[2];
    const float av3 = acA[3] + acB[3];

    // ---- in-wave shfl transpose: gv[g] = D[ebl][g*4+ej] (r10/r11-validated) ----
    float gv[4];
#pragma unroll
    for (int g = 0; g < 4; ++g) {
      const int srcl = shbase + g * 4;
      const float t0v = __shfl(av0, srcl);
      const float t1v = __shfl(av1, srcl);
      const float t2v = __shfl(av2, srcl);
      const float t3v = __shfl(av3, srcl);
      gv[g] = (ersel == 0) ? t0v : (ersel == 1) ? t1v : (ersel == 2) ? t2v : t3v;
    }

    // ---- gates + state update ----
    const float ig = sigmoidf_(x0 + gv[0]);
    const float fg = sigmoidf_(x1 + gv[1]);
    const float gg = tanhf_(x2 + gv[2]);
    const float og = sigmoidf_(x3 + gv[3]);
    cstate = fg * cstate + ig * gg;
    const float hval = og * tanhf_(cstate);

    const _Float16 hf = (_Float16)hval;
    unsigned short hb;
    __builtin_memcpy(&hb, &hf, 2);
    __hip_atomic_store(hwr + (size_t)eb * H_ + eu, hb,  // write-through
                       __ATOMIC_RELAXED, __HIP_MEMORY_SCOPE_AGENT);
    out[((size_t)eb * S_ + t) * H_ + eu] = hval;        // parallel ack

    __syncthreads();   // drain all 8 waves' h stores (acked at MALL)

    if (tid == 0)      // publish: one write-through WG flag
      __hip_atomic_store(flg + (size_t)(t + 1) * 64 + wg, 1u,
                         __ATOMIC_RELAXED, __HIP_MEMORY_SCOPE_AGENT);
  }

  cbuf[(size_t)eb * H_ + eu] = cstate;
}

// ---------------- host ----------------
extern "C" void kernel_launch(void* const* d_in, const int* in_sizes, int n_in,
                              void* d_out, int out_size, void* d_ws, size_t ws_size,
                              hipStream_t stream) {
  const int*   src = (const int*)d_in[0];
  const float* emb = (const float*)d_in[1];
  const float* Wih = (const float*)d_in[2];
  const float* Whh = (const float*)d_in[3];
  const float* bih = (const float*)d_in[4];
  const float* bhh = (const float*)d_in[5];
  float* out = (float*)d_out;

  // ws: [cbuf 128K][flg (S+1)*64*4][Wt 8M][Wt2 4M][hring][Af16][xg f16]
  char* ws = (char*)d_ws;
  float*    cbuf = (float*)ws;                          // 131072
  unsigned* flg  = (unsigned*)(ws + 131072);            // 513*64*4 = 131328
  const size_t stateBytes = 131072 + 131328;            // 262400
  _Float16* Wt  = (_Float16*)(ws + stateBytes);                 // 8 MB
  _Float16* Wt2 = (_Float16*)(ws + stateBytes + 8388608);       // 4 MB
  const size_t fixedBytes = stateBytes + 8388608 + 4194304;

  int chunk = 0;
  const int cand[4] = {512, 256, 128, 64};
  for (int ci = 0; ci < 4; ++ci) {
    size_t need = fixedBytes + (size_t)(cand[ci] + 1) * (BH_ * 2)   // hring
                  + (size_t)cand[ci] * B_ * E_ * 2                  // Af16
                  + (size_t)cand[ci] * B_ * G_ * 2;                 // xg f16
    if (need <= ws_size) { chunk = cand[ci]; break; }
  }
  if (chunk == 0) return;  // fail loud

  unsigned short* hring = (unsigned short*)(ws + fixedBytes);
  _Float16* Af16 = (_Float16*)(ws + fixedBytes + (size_t)(chunk + 1) * (BH_ * 2));
  _Float16* xg   = (_Float16*)(ws + fixedBytes + (size_t)(chunk + 1) * (BH_ * 2)
                               + (size_t)chunk * B_ * E_ * 2);

  (void)hipMemsetAsync(ws, 0, stateBytes, stream);   // c0 = 0, all flags = 0
  (void)hipMemsetAsync(flg, 1, 256, stream);         // seed flags[t=0][0..63]
  (void)hipMemsetAsync(hring, 0, BH_ * 2, stream);   // h0 = 0 (ring slot 0)

  int K1 = H_, K2 = E_;
  wt_kernel<<<dim3(64, 16), 256, 0, stream>>>(Whh, Wt, K1);
  wt_kernel<<<dim3(64, 8), 256, 0, stream>>>(Wih, Wt2, K2);

  for (int t0 = 0; t0 < S_; t0 += chunk) {
    gather_a<<<dim3(chunk * B_), 128, 0, stream>>>(src, emb, Af16, t0);
    xgates_mfma<<<dim3(G_ / 128, chunk * B_ / 128), 256, 0, stream>>>(
        Af16, Wt2, bih, bhh, xg);

    int nt = chunk;
    void* args[] = {(void*)&Wt, (void*)&xg, (void*)&hring, (void*)&cbuf,
                    (void*)&flg, (void*)&out, (void*)&t0, (void*)&nt};
    (void)hipLaunchCooperativeKernel((void*)lstm_wave, dim3(NWG), dim3(RTHR),
                                     args, 0u, stream);
  }
}

// Round 13
// 5485.990 us; speedup vs baseline: 1.8043x; 1.1137x over previous
//
#include <hip/hip_runtime.h>
#include <math.h>

// LSTM encoder: B=32, S=512, E=512, H=1024, G=4H=4096.
// Round 13: TAGGED-H recurrence — the h data carries its own step tag
// (u32 = (t<<16)|f16). Consumer's h load IS the poll: no flags, no acks,
// no publish stores. WG = (8 units, 16-batch half): reads half the h image;
// batch halves fully decoupled. One __syncthreads/step, partials double-
// buffered; waves 2-7 poll t+1 while waves 0-1 run the epilogue.
// All primitives validated r4-r12: write-through atomic u32 stores,
// relaxed atomic u64 load polls, MFMA frag maps (r5), shfl-free epilogue.

#define B_ 32
#define S_ 512
#define E_ 512
#define H_ 1024
#define G_ 4096
#define NWG 256
#define RTHR 512
#define BH_ (B_ * H_)    // u32 elements per h slot
#define XGPAD 40

typedef _Float16 f16x8 __attribute__((ext_vector_type(8)));
typedef _Float16 f16x4 __attribute__((ext_vector_type(4)));
typedef float f32x4 __attribute__((ext_vector_type(4)));
typedef unsigned long long u64;

__device__ __forceinline__ float sigmoidf_(float x) {
  return 1.0f / (1.0f + __expf(-x));
}
__device__ __forceinline__ float tanhf_(float x) {
  return 1.0f - 2.0f / (__expf(2.0f * x) + 1.0f);
}
__device__ __forceinline__ unsigned pack_(u64 q) {   // two tagged u32 -> f16x2 bits
  return (unsigned)(q & 0xFFFFu) | ((unsigned)(q >> 16) & 0xFFFF0000u);
}

// ---- one-time: W f32[K][4096] -> Wt f16[4096][K] ----
__global__ __launch_bounds__(256) void wt_kernel(
    const float* __restrict__ W, _Float16* __restrict__ Wt, int K)
{
  __shared__ float Lt[64][65];
  const int c0 = blockIdx.x * 64;
  const int k0 = blockIdx.y * 64;
  const int tid = threadIdx.x;
  const int colL = tid & 63;
  const int rq = tid >> 6;
#pragma unroll 4
  for (int p = 0; p < 16; ++p) {
    int r = p * 4 + rq;
    Lt[colL][r] = W[(size_t)(k0 + r) * G_ + c0 + colL];
  }
  __syncthreads();
  const int col = tid >> 2;
  const int kq = (tid & 3) * 16;
  _Float16 tmp[16];
#pragma unroll
  for (int i = 0; i < 16; ++i) tmp[i] = (_Float16)Lt[col][kq + i];
  *(f16x8*)(Wt + (size_t)(c0 + col) * K + k0 + kq)     = *(f16x8*)&tmp[0];
  *(f16x8*)(Wt + (size_t)(c0 + col) * K + k0 + kq + 8) = *(f16x8*)&tmp[8];
}

// ---- gather embedding rows -> f16 A[chunk*32][512] ----
__global__ __launch_bounds__(128) void gather_a(
    const int* __restrict__ src, const float* __restrict__ emb,
    _Float16* __restrict__ A, int t0)
{
  const int r = blockIdx.x;
  const int t = t0 + (r >> 5), b = r & 31;
  const int vrow = src[b * S_ + t];
  const float4 v = *(const float4*)(emb + (size_t)vrow * E_ + threadIdx.x * 4);
  f16x4 o = { (_Float16)v.x, (_Float16)v.y, (_Float16)v.z, (_Float16)v.w };
  *(f16x4*)(A + (size_t)r * E_ + threadIdx.x * 4) = o;
}

// ---- Phase A: x-gates f16 MFMA GEMM (r9-validated) ----
__global__ __launch_bounds__(256) void xgates_mfma(
    const _Float16* __restrict__ A, const _Float16* __restrict__ Bw,
    const float* __restrict__ bih, const float* __restrict__ bhh,
    _Float16* __restrict__ xg)
{
  __shared__ _Float16 Al[128][XGPAD];
  __shared__ _Float16 Bl[128][XGPAD];
  const int tid = threadIdx.x;
  const int row0 = blockIdx.y * 128;
  const int col0 = blockIdx.x * 128;
  const int wave = tid >> 6, lane = tid & 63;
  const int wm = wave >> 1, wn = wave & 1;
  const int lrow = lane & 15, lhi = lane >> 4;

  float bias[4];
#pragma unroll
  for (int n = 0; n < 4; ++n) {
    int c = col0 + wn * 64 + n * 16 + lrow;
    bias[n] = bih[c] + bhh[c];
  }
  f32x4 acc[4][4];
#pragma unroll
  for (int m = 0; m < 4; ++m)
#pragma unroll
    for (int n = 0; n < 4; ++n)
      acc[m][n] = (f32x4){bias[n], bias[n], bias[n], bias[n]};

  for (int kt = 0; kt < E_ / 32; ++kt) {
#pragma unroll
    for (int p = 0; p < 2; ++p) {
      int cch = tid * 2 + p;
      int rr = cch >> 2, kc = cch & 3;
      *(f16x8*)&Al[rr][kc * 8] =
          *(const f16x8*)(A + (size_t)(row0 + rr) * E_ + kt * 32 + kc * 8);
      *(f16x8*)&Bl[rr][kc * 8] =
          *(const f16x8*)(Bw + (size_t)(col0 + rr) * E_ + kt * 32 + kc * 8);
    }
    __syncthreads();
    f16x8 af[4], bfr[4];
#pragma unroll
    for (int m = 0; m < 4; ++m)
      af[m] = *(const f16x8*)&Al[wm * 64 + m * 16 + lrow][lhi * 8];
#pragma unroll
    for (int n = 0; n < 4; ++n)
      bfr[n] = *(const f16x8*)&Bl[wn * 64 + n * 16 + lrow][lhi * 8];
#pragma unroll
    for (int m = 0; m < 4; ++m)
#pragma unroll
      for (int n = 0; n < 4; ++n)
        acc[m][n] = __builtin_amdgcn_mfma_f32_16x16x32_f16(af[m], bfr[n],
                                                           acc[m][n], 0, 0, 0);
    __syncthreads();
  }
#pragma unroll
  for (int m = 0; m < 4; ++m)
#pragma unroll
    for (int n = 0; n < 4; ++n) {
      const int ccol = col0 + wn * 64 + n * 16 + lrow;
#pragma unroll
      for (int r = 0; r < 4; ++r) {
        const int rrow = row0 + wm * 64 + m * 16 + lhi * 4 + r;
        xg[(size_t)rrow * G_ + ccol] = (_Float16)acc[m][n][r];
      }
    }
}

// ---- Phase R: tagged-h recurrent kernel ----
// WG (bt = wg>>7, ug = wg&127): batches bt*16..+16, units ug*8..+8 (32 cols).
// Wave kq (0..7): K slice [kq*128, +128). D[16b x 32c]; partials in LDS.
#define LDQ(i) q##i = __hip_atomic_load(                                    \
    hq + (((i) >> 2) * 16 + ((i) & 3)), __ATOMIC_RELAXED,                   \
    __HIP_MEMORY_SCOPE_AGENT);
#define XOR8(a,b,c,d,e,f,g,h) (((a)|(b))|((c)|(d)))|(((e)|(f))|((g)|(h)))

__global__ __launch_bounds__(RTHR, 2) void lstm_tag(
    const _Float16* __restrict__ Wt, const _Float16* __restrict__ xg,
    unsigned* hbuf, float* cbuf, float* out, int t0, int nt)
{
  __shared__ float red[2][8][16][33];   // [slot][kq][b_local][col] 33792 B

  const int wg = blockIdx.x;
  const int tid = threadIdx.x;
  const int bt = wg >> 7;              // batch half
  const int ug = wg & 127;             // unit group
  const int U0 = ug * 8;

  const int wave = tid >> 6;
  const int lane = tid & 63;
  const int lrow = lane & 15, lhi = lane >> 4;
  const int kq = wave;

  // B fragments: 2 col-tiles x 4 ksteps = 32 VGPR/lane (constant-indexed)
  f16x8 bfr[2][4];
#pragma unroll
  for (int ct = 0; ct < 2; ++ct) {
    const int c = ct * 16 + lrow;                       // 0..31
    const int gcol = (c >> 3) * H_ + U0 + (c & 7);
#pragma unroll
    for (int s = 0; s < 4; ++s)
      bfr[ct][s] = *(const f16x8*)(Wt + (size_t)gcol * H_ + kq * 128 + s * 32 + lhi * 8);
  }

  // epilogue mapping (tid<128): b_local = tid>>3, j = tid&7
  const int bl = tid >> 3, ej = tid & 7;
  const int eb = bt * 16 + bl;
  const int eu = U0 + ej;
  float cstate = 0.f;
  if (tid < 128) cstate = cbuf[(size_t)eb * H_ + eu];

  float xv0 = 0.f, xv1 = 0.f, xv2 = 0.f, xv3 = 0.f;
  if (tid < 128) {
    const _Float16* xp = xg + (size_t)eb * G_ + eu;
    xv0 = (float)xp[0];      xv1 = (float)xp[H_];
    xv2 = (float)xp[2 * H_]; xv3 = (float)xp[3 * H_];
  }

  // per-lane h fragment base (u64 units): row = bt*16+lrow, k base kq*128+lhi*8
  const size_t rowOff64 = (size_t)(bt * 16 + lrow) * (H_ / 2) + kq * 64 + lhi * 4;

  for (int t = t0; t < t0 + nt; ++t) {
    const int lt = t - t0;
    const int slot = t & 1, nslot = slot ^ 1;
    const u64* hq = (const u64*)hbuf + (size_t)slot * (BH_ / 2) + rowOff64;

    // ---- poll+load own fragment: 16 tagged u64, retry until all tags==t ----
    u64 q0, q1, q2, q3, q4, q5, q6, q7, q8, q9, q10, q11, q12, q13, q14, q15;
    {
      const u64 expect = ((u64)(unsigned)t << 16) | ((u64)(unsigned)t << 48);
      int guard = 0;
      for (;;) {
        LDQ(0)  LDQ(1)  LDQ(2)  LDQ(3)  LDQ(4)  LDQ(5)  LDQ(6)  LDQ(7)
        LDQ(8)  LDQ(9)  LDQ(10) LDQ(11) LDQ(12) LDQ(13) LDQ(14) LDQ(15)
        const u64 bad =
            (XOR8(q0 ^ expect, q1 ^ expect, q2 ^ expect, q3 ^ expect,
                  q4 ^ expect, q5 ^ expect, q6 ^ expect, q7 ^ expect) |
             XOR8(q8 ^ expect, q9 ^ expect, q10 ^ expect, q11 ^ expect,
                  q12 ^ expect, q13 ^ expect, q14 ^ expect, q15 ^ expect)) &
            0xFFFF0000FFFF0000ULL;
        if (__all(bad == 0ULL)) break;
        __builtin_amdgcn_s_sleep(1);
        if (++guard > (1 << 20)) break;   // bounded: fail loud, never hang
      }
    }

    // ---- assemble f16x8 A-frags and run 8 MFMA (2 col-tiles x 4 ksteps) ----
    f32x4 acc0 = {0.f, 0.f, 0.f, 0.f};
    f32x4 acc1 = {0.f, 0.f, 0.f, 0.f};
#define KSTEP(s, qa, qb, qc, qd)                                              \
    {                                                                         \
      unsigned pu[4] = { pack_(qa), pack_(qb), pack_(qc), pack_(qd) };        \
      f16x8 av;                                                               \
      __builtin_memcpy(&av, pu, 16);                                          \
      acc0 = __builtin_amdgcn_mfma_f32_16x16x32_f16(av, bfr[0][s], acc0, 0, 0, 0); \
      acc1 = __builtin_amdgcn_mfma_f32_16x16x32_f16(av, bfr[1][s], acc1, 0, 0, 0); \
    }
    KSTEP(0, q0, q1, q2, q3)
    KSTEP(1, q4, q5, q6, q7)
    KSTEP(2, q8, q9, q10, q11)
    KSTEP(3, q12, q13, q14, q15)
#undef KSTEP

    // ---- partials (D layout r5-validated: row=lhi*4+r, col=lrow) ----
#pragma unroll
    for (int r = 0; r < 4; ++r) {
      red[slot][kq][lhi * 4 + r][lrow]      = acc0[r];
      red[slot][kq][lhi * 4 + r][16 + lrow] = acc1[r];
    }
    __syncthreads();   // the ONLY barrier per step

    if (tid < 128) {
      float g0 = xv0, g1 = xv1, g2 = xv2, g3 = xv3;
#pragma unroll
      for (int k8 = 0; k8 < 8; ++k8) {
        const float* rp = &red[slot][k8][bl][0];
        g0 += rp[ej];
        g1 += rp[8 + ej];
        g2 += rp[16 + ej];
        g3 += rp[24 + ej];
      }
      const float ig = sigmoidf_(g0);
      const float fg = sigmoidf_(g1);
      const float gg = tanhf_(g2);
      const float og = sigmoidf_(g3);
      cstate = fg * cstate + ig * gg;
      const float hval = og * tanhf_(cstate);

      const _Float16 hf = (_Float16)hval;
      unsigned short hb;
      __builtin_memcpy(&hb, &hf, 2);
      const unsigned hu = ((unsigned)(t + 1) << 16) | (unsigned)hb;
      __hip_atomic_store(hbuf + (size_t)nslot * BH_ + (size_t)eb * H_ + eu, hu,
                         __ATOMIC_RELAXED, __HIP_MEMORY_SCOPE_AGENT);
      out[((size_t)eb * S_ + t) * H_ + eu] = hval;   // off critical path

      // prefetch next step's xg (consumed next iteration)
      const int nlt = (lt == nt - 1) ? lt : lt + 1;
      const _Float16* xp = xg + ((size_t)nlt * B_ + eb) * G_ + eu;
      xv0 = (float)xp[0];      xv1 = (float)xp[H_];
      xv2 = (float)xp[2 * H_]; xv3 = (float)xp[3 * H_];
    }
  }

  if (tid < 128) cbuf[(size_t)eb * H_ + eu] = cstate;
}

// ---------------- host ----------------
extern "C" void kernel_launch(void* const* d_in, const int* in_sizes, int n_in,
                              void* d_out, int out_size, void* d_ws, size_t ws_size,
                              hipStream_t stream) {
  const int*   src = (const int*)d_in[0];
  const float* emb = (const float*)d_in[1];
  const float* Wih = (const float*)d_in[2];
  const float* Whh = (const float*)d_in[3];
  const float* bih = (const float*)d_in[4];
  const float* bhh = (const float*)d_in[5];
  float* out = (float*)d_out;

  // ws: [cbuf 128K][hbuf 2*128K][Wt 8M][Wt2 4M][Af16][xg f16]
  char* ws = (char*)d_ws;
  float*    cbuf = (float*)ws;                          // 131072
  unsigned* hbuf = (unsigned*)(ws + 131072);            // 2*BH_*4 = 262144
  const size_t stateBytes = 131072 + 262144;            // 393216
  _Float16* Wt  = (_Float16*)(ws + stateBytes);                 // 8 MB
  _Float16* Wt2 = (_Float16*)(ws + stateBytes + 8388608);       // 4 MB
  const size_t fixedBytes = stateBytes + 8388608 + 4194304;

  int chunk = 0;
  const int cand[4] = {512, 256, 128, 64};
  for (int ci = 0; ci < 4; ++ci) {
    size_t need = fixedBytes + (size_t)cand[ci] * B_ * E_ * 2     // Af16
                  + (size_t)cand[ci] * B_ * G_ * 2;               // xg f16
    if (need <= ws_size) { chunk = cand[ci]; break; }
  }
  if (chunk == 0) return;  // fail loud

  _Float16* Af16 = (_Float16*)(ws + fixedBytes);
  _Float16* xg   = (_Float16*)(ws + fixedBytes + (size_t)chunk * B_ * E_ * 2);

  (void)hipMemsetAsync(ws, 0, stateBytes, stream);   // c0 = 0; hbuf slot0 tag0/h0

  int K1 = H_, K2 = E_;
  wt_kernel<<<dim3(64, 16), 256, 0, stream>>>(Whh, Wt, K1);
  wt_kernel<<<dim3(64, 8), 256, 0, stream>>>(Wih, Wt2, K2);

  for (int t0 = 0; t0 < S_; t0 += chunk) {
    gather_a<<<dim3(chunk * B_), 128, 0, stream>>>(src, emb, Af16, t0);
    xgates_mfma<<<dim3(G_ / 128, chunk * B_ / 128), 256, 0, stream>>>(
        Af16, Wt2, bih, bhh, xg);

    int nt = chunk;
    void* args[] = {(void*)&Wt, (void*)&xg, (void*)&hbuf, (void*)&cbuf,
                    (void*)&out, (void*)&t0, (void*)&nt};
    (void)hipLaunchCooperativeKernel((void*)lstm_tag, dim3(NWG), dim3(RTHR),
                                     args, 0u, stream);
  }
}

// Round 14
// 3166.451 us; speedup vs baseline: 3.1260x; 1.7325x over previous
//
#include <hip/hip_runtime.h>
#include <math.h>

// LSTM encoder: B=32, S=512, E=512, H=1024, G=4H=4096.
// Round 14 = proven-sync (r9) x proven-geometry (r13):
//   - WG = (batch-half ht, 8 units): halves fully decoupled -> 128-WG sync
//     domains (was 256), per-WG h read halves (32KB/step)
//   - sync: wave0 polls 128 step-indexed flags (2 loads/lane), write-through
//     u16 h stores, first-touch h ring, tid0 flag publish (all r9-validated)
//   - NO tagged data (r13 lesson: polls = single words, data moves once)

#define B_ 32
#define S_ 512
#define E_ 512
#define H_ 1024
#define G_ 4096
#define NWG 256
#define RTHR 512
#define BH_ (B_ * H_)
#define XGPAD 40

typedef _Float16 f16x8 __attribute__((ext_vector_type(8)));
typedef _Float16 f16x4 __attribute__((ext_vector_type(4)));
typedef float f32x4 __attribute__((ext_vector_type(4)));

__device__ __forceinline__ float sigmoidf_(float x) {
  return 1.0f / (1.0f + __expf(-x));
}
__device__ __forceinline__ float tanhf_(float x) {
  return 1.0f - 2.0f / (__expf(2.0f * x) + 1.0f);
}

// ---- one-time: W f32[K][4096] -> Wt f16[4096][K] ----
__global__ __launch_bounds__(256) void wt_kernel(
    const float* __restrict__ W, _Float16* __restrict__ Wt, int K)
{
  __shared__ float Lt[64][65];
  const int c0 = blockIdx.x * 64;
  const int k0 = blockIdx.y * 64;
  const int tid = threadIdx.x;
  const int colL = tid & 63;
  const int rq = tid >> 6;
#pragma unroll 4
  for (int p = 0; p < 16; ++p) {
    int r = p * 4 + rq;
    Lt[colL][r] = W[(size_t)(k0 + r) * G_ + c0 + colL];
  }
  __syncthreads();
  const int col = tid >> 2;
  const int kq = (tid & 3) * 16;
  _Float16 tmp[16];
#pragma unroll
  for (int i = 0; i < 16; ++i) tmp[i] = (_Float16)Lt[col][kq + i];
  *(f16x8*)(Wt + (size_t)(c0 + col) * K + k0 + kq)     = *(f16x8*)&tmp[0];
  *(f16x8*)(Wt + (size_t)(c0 + col) * K + k0 + kq + 8) = *(f16x8*)&tmp[8];
}

// ---- gather embedding rows -> f16 A[chunk*32][512] ----
__global__ __launch_bounds__(128) void gather_a(
    const int* __restrict__ src, const float* __restrict__ emb,
    _Float16* __restrict__ A, int t0)
{
  const int r = blockIdx.x;
  const int t = t0 + (r >> 5), b = r & 31;
  const int vrow = src[b * S_ + t];
  const float4 v = *(const float4*)(emb + (size_t)vrow * E_ + threadIdx.x * 4);
  f16x4 o = { (_Float16)v.x, (_Float16)v.y, (_Float16)v.z, (_Float16)v.w };
  *(f16x4*)(A + (size_t)r * E_ + threadIdx.x * 4) = o;
}

// ---- Phase A: x-gates f16 MFMA GEMM (r9-validated) ----
__global__ __launch_bounds__(256) void xgates_mfma(
    const _Float16* __restrict__ A, const _Float16* __restrict__ Bw,
    const float* __restrict__ bih, const float* __restrict__ bhh,
    _Float16* __restrict__ xg)
{
  __shared__ _Float16 Al[128][XGPAD];
  __shared__ _Float16 Bl[128][XGPAD];
  const int tid = threadIdx.x;
  const int row0 = blockIdx.y * 128;
  const int col0 = blockIdx.x * 128;
  const int wave = tid >> 6, lane = tid & 63;
  const int wm = wave >> 1, wn = wave & 1;
  const int lrow = lane & 15, lhi = lane >> 4;

  float bias[4];
#pragma unroll
  for (int n = 0; n < 4; ++n) {
    int c = col0 + wn * 64 + n * 16 + lrow;
    bias[n] = bih[c] + bhh[c];
  }
  f32x4 acc[4][4];
#pragma unroll
  for (int m = 0; m < 4; ++m)
#pragma unroll
    for (int n = 0; n < 4; ++n)
      acc[m][n] = (f32x4){bias[n], bias[n], bias[n], bias[n]};

  for (int kt = 0; kt < E_ / 32; ++kt) {
#pragma unroll
    for (int p = 0; p < 2; ++p) {
      int cch = tid * 2 + p;
      int rr = cch >> 2, kc = cch & 3;
      *(f16x8*)&Al[rr][kc * 8] =
          *(const f16x8*)(A + (size_t)(row0 + rr) * E_ + kt * 32 + kc * 8);
      *(f16x8*)&Bl[rr][kc * 8] =
          *(const f16x8*)(Bw + (size_t)(col0 + rr) * E_ + kt * 32 + kc * 8);
    }
    __syncthreads();
    f16x8 af[4], bfr[4];
#pragma unroll
    for (int m = 0; m < 4; ++m)
      af[m] = *(const f16x8*)&Al[wm * 64 + m * 16 + lrow][lhi * 8];
#pragma unroll
    for (int n = 0; n < 4; ++n)
      bfr[n] = *(const f16x8*)&Bl[wn * 64 + n * 16 + lrow][lhi * 8];
#pragma unroll
    for (int m = 0; m < 4; ++m)
#pragma unroll
      for (int n = 0; n < 4; ++n)
        acc[m][n] = __builtin_amdgcn_mfma_f32_16x16x32_f16(af[m], bfr[n],
                                                           acc[m][n], 0, 0, 0);
    __syncthreads();
  }
#pragma unroll
  for (int m = 0; m < 4; ++m)
#pragma unroll
    for (int n = 0; n < 4; ++n) {
      const int ccol = col0 + wn * 64 + n * 16 + lrow;
#pragma unroll
      for (int r = 0; r < 4; ++r) {
        const int rrow = row0 + wm * 64 + m * 16 + lhi * 4 + r;
        xg[(size_t)rrow * G_ + ccol] = (_Float16)acc[m][n][r];
      }
    }
}

// ---- Phase R: half-decoupled recurrent kernel ----
// WG (ht = wg>>7, rem = wg&127): batches ht*16..+16, units U0..U0+8 (32 cols).
// Wave kq (0..7): K slice 128; 8 MFMA (4 ksteps x 2 coltiles). D = 16b x 32c.
__global__ __launch_bounds__(RTHR) void lstm_half(
    const _Float16* __restrict__ Wt, const _Float16* __restrict__ xg,
    unsigned short* hring, float* cbuf, unsigned* flg,
    float* out, int t0, int nt)
{
  __shared__ float red[8][16][33];   // [kq][b_local][col32+pad] 16896 B

  const int wg = blockIdx.x;
  const int tid = threadIdx.x;
  const int ht  = wg >> 7;             // batch half (decoupled domains)
  const int rem = wg & 127;            // unit group
  const int U0  = 8 * ((rem & 7) * 16 + (rem >> 3));   // XCD-contiguous units

  const int wave = tid >> 6;
  const int lane = tid & 63;
  const int lrow = lane & 15, lhi = lane >> 4;
  const int kq = wave;

  // B fragments: 2 coltiles x 4 ksteps = 32 VGPR/lane (r13-validated, promotes)
  f16x8 bfr[2][4];
#pragma unroll
  for (int ct = 0; ct < 2; ++ct) {
    const int c = ct * 16 + lrow;                     // col 0..31
    const int gcol = (c >> 3) * H_ + U0 + (c & 7);    // gate=c>>3, unit=c&7
#pragma unroll
    for (int s = 0; s < 4; ++s)
      bfr[ct][s] = *(const f16x8*)(Wt + (size_t)gcol * H_ + kq * 128 + s * 32 + lhi * 8);
  }

  // epilogue mapping (tid<128): b_local = tid>>3, unit j = tid&7
  const int bl = tid >> 3, ej = tid & 7;
  const int eb = ht * 16 + bl;
  const int eu = U0 + ej;
  float cstate = 0.f;
  if (tid < 128) cstate = cbuf[(size_t)eb * H_ + eu];

  float xv0 = 0.f, xv1 = 0.f, xv2 = 0.f, xv3 = 0.f;
  if (tid < 128) {
    const _Float16* xp = xg + (size_t)eb * G_ + eu;
    xv0 = (float)xp[0];      xv1 = (float)xp[H_];
    xv2 = (float)xp[2 * H_]; xv3 = (float)xp[3 * H_];
  }

  for (int t = t0; t < t0 + nt; ++t) {
    const int lt = t - t0;
    const _Float16* hrd = (const _Float16*)hring + (size_t)lt * BH_;   // first touch
    unsigned short* hwr = hring + (size_t)((lt == nt - 1) ? 0 : lt + 1) * BH_;

    // ---- gate: wave 0 polls its half's 128 flags (2 loads/lane) ----
    if (wave == 0) {
      const unsigned* fp = flg + (size_t)t * 256 + ht * 128 + lane;
      int guard = 0;
      for (;;) {
        unsigned a0 = __hip_atomic_load(fp, __ATOMIC_RELAXED,
                                        __HIP_MEMORY_SCOPE_AGENT);
        unsigned a1 = __hip_atomic_load(fp + 64, __ATOMIC_RELAXED,
                                        __HIP_MEMORY_SCOPE_AGENT);
        if (__all((a0 & a1) != 0u)) break;
        __builtin_amdgcn_s_sleep(1);
        if (++guard > (1 << 22)) break;   // bounded: fail loud, never hang
      }
    }
    __syncthreads();   // A: h[t] of this half is visible

    // ---- 8 MFMA: A rows = h[ht*16 + lrow], K slice kq*128 ----
    const _Float16* hp = hrd + (size_t)(ht * 16 + lrow) * H_ + kq * 128 + lhi * 8;
    f32x4 acc0 = {0.f, 0.f, 0.f, 0.f};
    f32x4 acc1 = {0.f, 0.f, 0.f, 0.f};
#pragma unroll
    for (int s = 0; s < 4; ++s) {
      const f16x8 av = *(const f16x8*)(hp + s * 32);
      acc0 = __builtin_amdgcn_mfma_f32_16x16x32_f16(av, bfr[0][s], acc0, 0, 0, 0);
      acc1 = __builtin_amdgcn_mfma_f32_16x16x32_f16(av, bfr[1][s], acc1, 0, 0, 0);
    }

    // ---- partials (D layout r5-validated: row=lhi*4+r, col=lrow) ----
#pragma unroll
    for (int r = 0; r < 4; ++r) {
      red[kq][lhi * 4 + r][lrow]      = acc0[r];
      red[kq][lhi * 4 + r][16 + lrow] = acc1[r];
    }
    __syncthreads();   // B

    if (tid < 128) {
      float g0 = xv0, g1 = xv1, g2 = xv2, g3 = xv3;
#pragma unroll
      for (int k8 = 0; k8 < 8; ++k8) {
        const float* rp = &red[k8][bl][0];
        g0 += rp[ej];
        g1 += rp[8 + ej];
        g2 += rp[16 + ej];
        g3 += rp[24 + ej];
      }
      const float ig = sigmoidf_(g0);
      const float fg = sigmoidf_(g1);
      const float gg = tanhf_(g2);
      const float og = sigmoidf_(g3);
      cstate = fg * cstate + ig * gg;
      const float hval = og * tanhf_(cstate);

      out[((size_t)eb * S_ + t) * H_ + eu] = hval;   // f32, pre-quantization
      const _Float16 hf = (_Float16)hval;
      unsigned short hb;
      __builtin_memcpy(&hb, &hf, 2);
      __hip_atomic_store(hwr + (size_t)eb * H_ + eu, hb,   // write-through
                         __ATOMIC_RELAXED, __HIP_MEMORY_SCOPE_AGENT);

      // prefetch next step's xg
      const int nlt = (lt == nt - 1) ? lt : lt + 1;
      const _Float16* xp = xg + ((size_t)nlt * B_ + eb) * G_ + eu;
      xv0 = (float)xp[0];      xv1 = (float)xp[H_];
      xv2 = (float)xp[2 * H_]; xv3 = (float)xp[3 * H_];
    }
    __syncthreads();   // C: all h stores acked at MALL (vmcnt drained per wave)

    if (tid == 0)      // publish: one write-through flag, no ack wait
      __hip_atomic_store(flg + (size_t)(t + 1) * 256 + ht * 128 + rem, 1u,
                         __ATOMIC_RELAXED, __HIP_MEMORY_SCOPE_AGENT);
  }

  if (tid < 128) cbuf[(size_t)eb * H_ + eu] = cstate;
}

// ---------------- host ----------------
extern "C" void kernel_launch(void* const* d_in, const int* in_sizes, int n_in,
                              void* d_out, int out_size, void* d_ws, size_t ws_size,
                              hipStream_t stream) {
  const int*   src = (const int*)d_in[0];
  const float* emb = (const float*)d_in[1];
  const float* Wih = (const float*)d_in[2];
  const float* Whh = (const float*)d_in[3];
  const float* bih = (const float*)d_in[4];
  const float* bhh = (const float*)d_in[5];
  float* out = (float*)d_out;

  // ws: [cbuf 128K][flg (S+1)*256*4][Wt 8M][Wt2 4M][hring][Af16][xg f16]
  char* ws = (char*)d_ws;
  float*    cbuf = (float*)ws;                          // 131072
  unsigned* flg  = (unsigned*)(ws + 131072);            // 513*256*4 = 525312
  const size_t stateBytes = 131072 + 525312;            // 656384
  _Float16* Wt  = (_Float16*)(ws + stateBytes);                 // 8 MB
  _Float16* Wt2 = (_Float16*)(ws + stateBytes + 8388608);       // 4 MB
  const size_t fixedBytes = stateBytes + 8388608 + 4194304;

  int chunk = 0;
  const int cand[4] = {512, 256, 128, 64};
  for (int ci = 0; ci < 4; ++ci) {
    size_t need = fixedBytes + (size_t)(cand[ci] + 1) * (BH_ * 2)   // hring
                  + (size_t)cand[ci] * B_ * E_ * 2                  // Af16
                  + (size_t)cand[ci] * B_ * G_ * 2;                 // xg f16
    if (need <= ws_size) { chunk = cand[ci]; break; }
  }
  if (chunk == 0) return;  // fail loud

  unsigned short* hring = (unsigned short*)(ws + fixedBytes);
  _Float16* Af16 = (_Float16*)(ws + fixedBytes + (size_t)(chunk + 1) * (BH_ * 2));
  _Float16* xg   = (_Float16*)(ws + fixedBytes + (size_t)(chunk + 1) * (BH_ * 2)
                               + (size_t)chunk * B_ * E_ * 2);

  (void)hipMemsetAsync(ws, 0, stateBytes, stream);   // c0 = 0, all flags = 0
  (void)hipMemsetAsync(flg, 1, 1024, stream);        // seed flags[t=0][0..255]
  (void)hipMemsetAsync(hring, 0, BH_ * 2, stream);   // h0 = 0 (ring slot 0)

  int K1 = H_, K2 = E_;
  wt_kernel<<<dim3(64, 16), 256, 0, stream>>>(Whh, Wt, K1);
  wt_kernel<<<dim3(64, 8), 256, 0, stream>>>(Wih, Wt2, K2);

  for (int t0 = 0; t0 < S_; t0 += chunk) {
    gather_a<<<dim3(chunk * B_), 128, 0, stream>>>(src, emb, Af16, t0);
    xgates_mfma<<<dim3(G_ / 128, chunk * B_ / 128), 256, 0, stream>>>(
        Af16, Wt2, bih, bhh, xg);

    int nt = chunk;
    void* args[] = {(void*)&Wt, (void*)&xg, (void*)&hring, (void*)&cbuf,
                    (void*)&flg, (void*)&out, (void*)&t0, (void*)&nt};
    (void)hipLaunchCooperativeKernel((void*)lstm_half, dim3(NWG), dim3(RTHR),
                                     args, 0u, stream);
  }
}

// Round 15
// 2831.358 us; speedup vs baseline: 3.4959x; 1.1184x over previous
//
#include <hip/hip_runtime.h>
#include <math.h>

// LSTM encoder: B=32, S=512, E=512, H=1024, G=4H=4096.
// Round 15 = champion r9 with the publish chain shortened:
//   - epilogue: h-store -> WAVE-LOCAL vmcnt(0) -> per-wave flag publish ->
//     THEN out store + xg prefetch (HBM write ack off the critical chain)
//   - barrier C deleted (red double-buffered by t&1; flag gating spaces
//     slot reuse >= 2 epilogues apart — see proof comment)
//   - barrier A deleted (wave0 polls, LDS relay releases waves 1-7)
// All primitives individually validated: WT atomic stores (r4+), u64 flag
// polls (r7), wave-local vmcnt publish (r7), LDS relay (r11), r9 geometry.

#define B_ 32
#define S_ 512
#define E_ 512
#define H_ 1024
#define G_ 4096
#define NWG 256
#define RTHR 512
#define BH_ (B_ * H_)
#define XGPAD 40

typedef _Float16 f16x8 __attribute__((ext_vector_type(8)));
typedef _Float16 f16x4 __attribute__((ext_vector_type(4)));
typedef float f32x4 __attribute__((ext_vector_type(4)));
typedef unsigned long long u64;

__device__ __forceinline__ float sigmoidf_(float x) {
  return 1.0f / (1.0f + __expf(-x));
}
__device__ __forceinline__ float tanhf_(float x) {
  return 1.0f - 2.0f / (__expf(2.0f * x) + 1.0f);
}

// ---- one-time: W f32[K][4096] -> Wt f16[4096][K] ----
__global__ __launch_bounds__(256) void wt_kernel(
    const float* __restrict__ W, _Float16* __restrict__ Wt, int K)
{
  __shared__ float Lt[64][65];
  const int c0 = blockIdx.x * 64;
  const int k0 = blockIdx.y * 64;
  const int tid = threadIdx.x;
  const int colL = tid & 63;
  const int rq = tid >> 6;
#pragma unroll 4
  for (int p = 0; p < 16; ++p) {
    int r = p * 4 + rq;
    Lt[colL][r] = W[(size_t)(k0 + r) * G_ + c0 + colL];
  }
  __syncthreads();
  const int col = tid >> 2;
  const int kq = (tid & 3) * 16;
  _Float16 tmp[16];
#pragma unroll
  for (int i = 0; i < 16; ++i) tmp[i] = (_Float16)Lt[col][kq + i];
  *(f16x8*)(Wt + (size_t)(c0 + col) * K + k0 + kq)     = *(f16x8*)&tmp[0];
  *(f16x8*)(Wt + (size_t)(c0 + col) * K + k0 + kq + 8) = *(f16x8*)&tmp[8];
}

// ---- gather embedding rows -> f16 A[chunk*32][512] ----
__global__ __launch_bounds__(128) void gather_a(
    const int* __restrict__ src, const float* __restrict__ emb,
    _Float16* __restrict__ A, int t0)
{
  const int r = blockIdx.x;
  const int t = t0 + (r >> 5), b = r & 31;
  const int vrow = src[b * S_ + t];
  const float4 v = *(const float4*)(emb + (size_t)vrow * E_ + threadIdx.x * 4);
  f16x4 o = { (_Float16)v.x, (_Float16)v.y, (_Float16)v.z, (_Float16)v.w };
  *(f16x4*)(A + (size_t)r * E_ + threadIdx.x * 4) = o;
}

// ---- Phase A: x-gates f16 MFMA GEMM (r9-validated) ----
__global__ __launch_bounds__(256) void xgates_mfma(
    const _Float16* __restrict__ A, const _Float16* __restrict__ Bw,
    const float* __restrict__ bih, const float* __restrict__ bhh,
    _Float16* __restrict__ xg)
{
  __shared__ _Float16 Al[128][XGPAD];
  __shared__ _Float16 Bl[128][XGPAD];
  const int tid = threadIdx.x;
  const int row0 = blockIdx.y * 128;
  const int col0 = blockIdx.x * 128;
  const int wave = tid >> 6, lane = tid & 63;
  const int wm = wave >> 1, wn = wave & 1;
  const int lrow = lane & 15, lhi = lane >> 4;

  float bias[4];
#pragma unroll
  for (int n = 0; n < 4; ++n) {
    int c = col0 + wn * 64 + n * 16 + lrow;
    bias[n] = bih[c] + bhh[c];
  }
  f32x4 acc[4][4];
#pragma unroll
  for (int m = 0; m < 4; ++m)
#pragma unroll
    for (int n = 0; n < 4; ++n)
      acc[m][n] = (f32x4){bias[n], bias[n], bias[n], bias[n]};

  for (int kt = 0; kt < E_ / 32; ++kt) {
#pragma unroll
    for (int p = 0; p < 2; ++p) {
      int cch = tid * 2 + p;
      int rr = cch >> 2, kc = cch & 3;
      *(f16x8*)&Al[rr][kc * 8] =
          *(const f16x8*)(A + (size_t)(row0 + rr) * E_ + kt * 32 + kc * 8);
      *(f16x8*)&Bl[rr][kc * 8] =
          *(const f16x8*)(Bw + (size_t)(col0 + rr) * E_ + kt * 32 + kc * 8);
    }
    __syncthreads();
    f16x8 af[4], bfr[4];
#pragma unroll
    for (int m = 0; m < 4; ++m)
      af[m] = *(const f16x8*)&Al[wm * 64 + m * 16 + lrow][lhi * 8];
#pragma unroll
    for (int n = 0; n < 4; ++n)
      bfr[n] = *(const f16x8*)&Bl[wn * 64 + n * 16 + lrow][lhi * 8];
#pragma unroll
    for (int m = 0; m < 4; ++m)
#pragma unroll
      for (int n = 0; n < 4; ++n)
        acc[m][n] = __builtin_amdgcn_mfma_f32_16x16x32_f16(af[m], bfr[n],
                                                           acc[m][n], 0, 0, 0);
    __syncthreads();
  }
#pragma unroll
  for (int m = 0; m < 4; ++m)
#pragma unroll
    for (int n = 0; n < 4; ++n) {
      const int ccol = col0 + wn * 64 + n * 16 + lrow;
#pragma unroll
      for (int r = 0; r < 4; ++r) {
        const int rrow = row0 + wm * 64 + m * 16 + lhi * 4 + r;
        xg[(size_t)rrow * G_ + ccol] = (_Float16)acc[m][n][r];
      }
    }
}

// ---- Phase R: r9 geometry, shortened publish chain ----
// WG: 4 units (16 gate cols); wave kq: K slice 128; D = 32b x 16c.
// Safety of barrier-C removal: wave w writes red[slot(t)] only after the
// t-gate (flags[t] observed). flags[t] publish happens AFTER epilogue t-1
// finished READING red[slot(t-1)], and epilogues are sequential on waves
// 0-1, so red[slot(t)] (== slot(t-2)) was last read at epilogue t-2, which
// completed before flags[t-1], which preceded flags[t]. No overlap.
__global__ __launch_bounds__(RTHR) void lstm_nb(
    const _Float16* __restrict__ Wt, const _Float16* __restrict__ xg,
    unsigned short* hring, float* cbuf, unsigned* flg,
    float* out, int t0, int nt)
{
  __shared__ float red[2][8 * 32 * 17];   // double-buffered partials, 34816 B
  __shared__ int relay;                   // step tag: wave0 -> waves 1-7

  const int wg = blockIdx.x;
  const int tid = threadIdx.x;
  const int J0 = 4 * ((wg & 7) * 32 + (wg >> 3));   // XCD-contiguous units

  const int wave = tid >> 6;
  const int lane = tid & 63;
  const int lrow = lane & 15;
  const int lhi  = lane >> 4;
  const int Kw   = wave * 128;
  const int gcol = (lrow >> 2) * H_ + J0 + (lrow & 3);

  if (tid == 0) relay = t0 - 1;
  __syncthreads();   // one-time init

  f16x8 bf[4];
#pragma unroll
  for (int s = 0; s < 4; ++s)
    bf[s] = *(const f16x8*)(Wt + (size_t)gcol * H_ + Kw + s * 32 + lhi * 8);

  const int bq = tid >> 2, jq = tid & 3;   // epilogue mapping (tid<128)
  float cstate = 0.f;
  if (tid < 128) cstate = cbuf[(size_t)bq * H_ + J0 + jq];

  float xv0 = 0.f, xv1 = 0.f, xv2 = 0.f, xv3 = 0.f;
  if (tid < 128) {
    const _Float16* xp = xg + (size_t)bq * G_ + J0 + jq;
    xv0 = (float)xp[0];      xv1 = (float)xp[H_];
    xv2 = (float)xp[2 * H_]; xv3 = (float)xp[3 * H_];
  }

  for (int t = t0; t < t0 + nt; ++t) {
    const int lt = t - t0;
    const int slot = t & 1;
    const _Float16* hrd = (const _Float16*)hring + (size_t)lt * BH_;   // first touch
    unsigned short* hwr = hring + (size_t)((lt == nt - 1) ? 0 : lt + 1) * BH_;

    // ---- gate: wave 0 polls 256 flag-PAIRS (4 u64/lane); LDS relay ----
    if (wave == 0) {
      const u64* fq = (const u64*)flg + (size_t)t * 256;
      int guard = 0;
      for (;;) {
        u64 a0 = __hip_atomic_load(fq + lane,       __ATOMIC_RELAXED, __HIP_MEMORY_SCOPE_AGENT);
        u64 a1 = __hip_atomic_load(fq + lane + 64,  __ATOMIC_RELAXED, __HIP_MEMORY_SCOPE_AGENT);
        u64 a2 = __hip_atomic_load(fq + lane + 128, __ATOMIC_RELAXED, __HIP_MEMORY_SCOPE_AGENT);
        u64 a3 = __hip_atomic_load(fq + lane + 192, __ATOMIC_RELAXED, __HIP_MEMORY_SCOPE_AGENT);
        unsigned m = (unsigned)a0 & (unsigned)(a0 >> 32)
                   & (unsigned)a1 & (unsigned)(a1 >> 32)
                   & (unsigned)a2 & (unsigned)(a2 >> 32)
                   & (unsigned)a3 & (unsigned)(a3 >> 32);
        if (__all(m != 0u)) break;
        __builtin_amdgcn_s_sleep(1);
        if (++guard > (1 << 22)) break;   // bounded: fail loud, never hang
      }
      if (lane == 0)
        __hip_atomic_store(&relay, t, __ATOMIC_RELAXED, __HIP_MEMORY_SCOPE_WORKGROUP);
    } else {
      int guard = 0;
      while (__hip_atomic_load(&relay, __ATOMIC_RELAXED,
                               __HIP_MEMORY_SCOPE_WORKGROUP) < t) {
        __builtin_amdgcn_s_sleep(1);
        if (++guard > (1 << 22)) break;   // bounded: fail loud, never hang
      }
    }
    asm volatile("" ::: "memory");   // no h-load hoisting above the gate

    // ---- 8 MFMA: rows lrow & 16+lrow, K slice Kw (r9-exact) ----
    f32x4 acc0 = {0.f, 0.f, 0.f, 0.f};
    f32x4 acc1 = {0.f, 0.f, 0.f, 0.f};
#pragma unroll
    for (int s = 0; s < 4; ++s) {
      f16x8 a0 = *(const f16x8*)(hrd + (size_t)lrow * H_ + Kw + s * 32 + lhi * 8);
      f16x8 a1 = *(const f16x8*)(hrd + (size_t)(16 + lrow) * H_ + Kw + s * 32 + lhi * 8);
      acc0 = __builtin_amdgcn_mfma_f32_16x16x32_f16(a0, bf[s], acc0, 0, 0, 0);
      acc1 = __builtin_amdgcn_mfma_f32_16x16x32_f16(a1, bf[s], acc1, 0, 0, 0);
    }

#pragma unroll
    for (int r = 0; r < 4; ++r) {
      red[slot][(wave * 32 + lhi * 4 + r) * 17 + lrow]      = acc0[r];
      red[slot][(wave * 32 + 16 + lhi * 4 + r) * 17 + lrow] = acc1[r];
    }
    __syncthreads();   // B: the ONLY per-step barrier

    if (tid < 128) {
      float g0 = xv0, g1 = xv1, g2 = xv2, g3 = xv3;
#pragma unroll
      for (int w = 0; w < 8; ++w) {
        const float* rp = &red[slot][(w * 32 + bq) * 17];
        g0 += rp[jq];
        g1 += rp[4 + jq];
        g2 += rp[8 + jq];
        g3 += rp[12 + jq];
      }
      const float ig = sigmoidf_(g0);
      const float fg = sigmoidf_(g1);
      const float gg = tanhf_(g2);
      const float og = sigmoidf_(g3);
      cstate = fg * cstate + ig * gg;
      const float hval = og * tanhf_(cstate);

      // publish chain: h-store -> wave-local ack -> flag. Nothing else drains.
      const _Float16 hf = (_Float16)hval;
      unsigned short hb;
      __builtin_memcpy(&hb, &hf, 2);
      __hip_atomic_store(hwr + (size_t)bq * H_ + J0 + jq, hb,
                         __ATOMIC_RELAXED, __HIP_MEMORY_SCOPE_AGENT);
      asm volatile("s_waitcnt vmcnt(0)" ::: "memory");   // waits h-stores only
      if (lane == 0)   // tid 0 (wave0) and tid 64 (wave1): per-wave flags
        __hip_atomic_store(flg + (size_t)(t + 1) * 512 + wg * 2 + wave, 1u,
                           __ATOMIC_RELAXED, __HIP_MEMORY_SCOPE_AGENT);

      // off the critical chain: out store + next-step xg prefetch
      out[((size_t)bq * S_ + t) * H_ + J0 + jq] = hval;
      const int nlt = (lt == nt - 1) ? lt : lt + 1;
      const _Float16* xp = xg + ((size_t)nlt * B_ + bq) * G_ + J0 + jq;
      xv0 = (float)xp[0];      xv1 = (float)xp[H_];
      xv2 = (float)xp[2 * H_]; xv3 = (float)xp[3 * H_];
    }
  }

  if (tid < 128) cbuf[(size_t)bq * H_ + J0 + jq] = cstate;
}

// ---------------- host ----------------
extern "C" void kernel_launch(void* const* d_in, const int* in_sizes, int n_in,
                              void* d_out, int out_size, void* d_ws, size_t ws_size,
                              hipStream_t stream) {
  const int*   src = (const int*)d_in[0];
  const float* emb = (const float*)d_in[1];
  const float* Wih = (const float*)d_in[2];
  const float* Whh = (const float*)d_in[3];
  const float* bih = (const float*)d_in[4];
  const float* bhh = (const float*)d_in[5];
  float* out = (float*)d_out;

  // ws: [cbuf 128K][flg (S+1)*512*4][Wt 8M][Wt2 4M][hring][Af16][xg f16]
  char* ws = (char*)d_ws;
  float*    cbuf = (float*)ws;                          // 131072
  unsigned* flg  = (unsigned*)(ws + 131072);            // 513*512*4 = 1050624
  const size_t stateBytes = 131072 + 1050624;           // 1181696
  _Float16* Wt  = (_Float16*)(ws + stateBytes);                 // 8 MB
  _Float16* Wt2 = (_Float16*)(ws + stateBytes + 8388608);       // 4 MB
  const size_t fixedBytes = stateBytes + 8388608 + 4194304;

  int chunk = 0;
  const int cand[4] = {512, 256, 128, 64};
  for (int ci = 0; ci < 4; ++ci) {
    size_t need = fixedBytes + (size_t)(cand[ci] + 1) * (BH_ * 2)   // hring
                  + (size_t)cand[ci] * B_ * E_ * 2                  // Af16
                  + (size_t)cand[ci] * B_ * G_ * 2;                 // xg f16
    if (need <= ws_size) { chunk = cand[ci]; break; }
  }
  if (chunk == 0) return;  // fail loud

  unsigned short* hring = (unsigned short*)(ws + fixedBytes);
  _Float16* Af16 = (_Float16*)(ws + fixedBytes + (size_t)(chunk + 1) * (BH_ * 2));
  _Float16* xg   = (_Float16*)(ws + fixedBytes + (size_t)(chunk + 1) * (BH_ * 2)
                               + (size_t)chunk * B_ * E_ * 2);

  (void)hipMemsetAsync(ws, 0, stateBytes, stream);   // c0 = 0, all flags = 0
  (void)hipMemsetAsync(flg, 1, 2048, stream);        // seed flags[t=0] (512 words)
  (void)hipMemsetAsync(hring, 0, BH_ * 2, stream);   // h0 = 0 (ring slot 0)

  int K1 = H_, K2 = E_;
  wt_kernel<<<dim3(64, 16), 256, 0, stream>>>(Whh, Wt, K1);
  wt_kernel<<<dim3(64, 8), 256, 0, stream>>>(Wih, Wt2, K2);

  for (int t0 = 0; t0 < S_; t0 += chunk) {
    gather_a<<<dim3(chunk * B_), 128, 0, stream>>>(src, emb, Af16, t0);
    xgates_mfma<<<dim3(G_ / 128, chunk * B_ / 128), 256, 0, stream>>>(
        Af16, Wt2, bih, bhh, xg);

    int nt = chunk;
    void* args[] = {(void*)&Wt, (void*)&xg, (void*)&hring, (void*)&cbuf,
                    (void*)&flg, (void*)&out, (void*)&t0, (void*)&nt};
    (void)hipLaunchCooperativeKernel((void*)lstm_nb, dim3(NWG), dim3(RTHR),
                                     args, 0u, stream);
  }
}

// Round 16
// 2629.477 us; speedup vs baseline: 3.7644x; 1.0768x over previous
//
#include <hip/hip_runtime.h>
#include <math.h>

// LSTM encoder: B=32, S=512, E=512, H=1024, G=4H=4096.
// FINAL (= round-9 champion, 2654 us total; restored after r10-r15 structural
// experiments all failed to beat its 5.18 us/step):
//   - xgates: f16 MFMA GEMM (gather_a + 128x128 tile), bias in acc-init
//   - recurrence: 256 WGs x 512 thr; WG owns 4 hidden units; wave kq holds
//     W frags (16 VGPR) for K slice 128; 8 MFMA/step; LDS K-reduce
//   - sync/step: wave0 polls 256 step-indexed flags -> barrier -> MFMA ->
//     LDS reduce -> gates -> write-through u16 h store -> barrier (drain) ->
//     tid0 flag publish. First-touch h ring; all-relaxed MALL atomics.
//   - measured floor: ~5.2 us/step = cross-XCD MALL coherence chain
//     (store-visible + publish/observe + reload + 256-WG tail); latency-bound
//     (VALUBusy 6%, MfmaUtil 2%, HBM 2%); 6 sync topologies converge here.

#define B_ 32
#define S_ 512
#define E_ 512
#define H_ 1024
#define G_ 4096
#define NWG 256
#define RTHR 512
#define BH_ (B_ * H_)
#define XGPAD 40

typedef _Float16 f16x8 __attribute__((ext_vector_type(8)));
typedef _Float16 f16x4 __attribute__((ext_vector_type(4)));
typedef float f32x4 __attribute__((ext_vector_type(4)));

__device__ __forceinline__ float sigmoidf_(float x) {
  return 1.0f / (1.0f + __expf(-x));
}
__device__ __forceinline__ float tanhf_(float x) {
  return 1.0f - 2.0f / (__expf(2.0f * x) + 1.0f);
}

// ---- one-time: W f32[K][4096] -> Wt f16[4096][K] (transpose + convert) ----
__global__ __launch_bounds__(256) void wt_kernel(
    const float* __restrict__ W, _Float16* __restrict__ Wt, int K)
{
  __shared__ float Lt[64][65];
  const int c0 = blockIdx.x * 64;
  const int k0 = blockIdx.y * 64;
  const int tid = threadIdx.x;
  const int colL = tid & 63;
  const int rq = tid >> 6;
#pragma unroll 4
  for (int p = 0; p < 16; ++p) {
    int r = p * 4 + rq;
    Lt[colL][r] = W[(size_t)(k0 + r) * G_ + c0 + colL];
  }
  __syncthreads();
  const int col = tid >> 2;
  const int kq = (tid & 3) * 16;
  _Float16 tmp[16];
#pragma unroll
  for (int i = 0; i < 16; ++i) tmp[i] = (_Float16)Lt[col][kq + i];
  *(f16x8*)(Wt + (size_t)(c0 + col) * K + k0 + kq)     = *(f16x8*)&tmp[0];
  *(f16x8*)(Wt + (size_t)(c0 + col) * K + k0 + kq + 8) = *(f16x8*)&tmp[8];
}

// ---- gather embedding rows -> f16 A[chunk*32][512] ----
__global__ __launch_bounds__(128) void gather_a(
    const int* __restrict__ src, const float* __restrict__ emb,
    _Float16* __restrict__ A, int t0)
{
  const int r = blockIdx.x;
  const int t = t0 + (r >> 5), b = r & 31;
  const int vrow = src[b * S_ + t];
  const float4 v = *(const float4*)(emb + (size_t)vrow * E_ + threadIdx.x * 4);
  f16x4 o = { (_Float16)v.x, (_Float16)v.y, (_Float16)v.z, (_Float16)v.w };
  *(f16x4*)(A + (size_t)r * E_ + threadIdx.x * 4) = o;
}

// ---- Phase A: x-gates f16 MFMA GEMM: xg = A[rows][512] * Wt2^T + bias ----
__global__ __launch_bounds__(256) void xgates_mfma(
    const _Float16* __restrict__ A, const _Float16* __restrict__ Bw,
    const float* __restrict__ bih, const float* __restrict__ bhh,
    _Float16* __restrict__ xg)
{
  __shared__ _Float16 Al[128][XGPAD];
  __shared__ _Float16 Bl[128][XGPAD];
  const int tid = threadIdx.x;
  const int row0 = blockIdx.y * 128;
  const int col0 = blockIdx.x * 128;
  const int wave = tid >> 6, lane = tid & 63;
  const int wm = wave >> 1, wn = wave & 1;
  const int lrow = lane & 15, lhi = lane >> 4;

  float bias[4];
#pragma unroll
  for (int n = 0; n < 4; ++n) {
    int c = col0 + wn * 64 + n * 16 + lrow;
    bias[n] = bih[c] + bhh[c];
  }
  f32x4 acc[4][4];
#pragma unroll
  for (int m = 0; m < 4; ++m)
#pragma unroll
    for (int n = 0; n < 4; ++n)
      acc[m][n] = (f32x4){bias[n], bias[n], bias[n], bias[n]};

  for (int kt = 0; kt < E_ / 32; ++kt) {
#pragma unroll
    for (int p = 0; p < 2; ++p) {     // 512 16B-chunks per tile pair, 2/thread
      int cch = tid * 2 + p;
      int rr = cch >> 2, kc = cch & 3;
      *(f16x8*)&Al[rr][kc * 8] =
          *(const f16x8*)(A + (size_t)(row0 + rr) * E_ + kt * 32 + kc * 8);
      *(f16x8*)&Bl[rr][kc * 8] =
          *(const f16x8*)(Bw + (size_t)(col0 + rr) * E_ + kt * 32 + kc * 8);
    }
    __syncthreads();
    f16x8 af[4], bfr[4];
#pragma unroll
    for (int m = 0; m < 4; ++m)
      af[m] = *(const f16x8*)&Al[wm * 64 + m * 16 + lrow][lhi * 8];
#pragma unroll
    for (int n = 0; n < 4; ++n)
      bfr[n] = *(const f16x8*)&Bl[wn * 64 + n * 16 + lrow][lhi * 8];
#pragma unroll
    for (int m = 0; m < 4; ++m)
#pragma unroll
      for (int n = 0; n < 4; ++n)
        acc[m][n] = __builtin_amdgcn_mfma_f32_16x16x32_f16(af[m], bfr[n],
                                                           acc[m][n], 0, 0, 0);
    __syncthreads();
  }
  // D layout (r5-validated): col = lane&15, row = (lane>>4)*4 + reg
#pragma unroll
  for (int m = 0; m < 4; ++m)
#pragma unroll
    for (int n = 0; n < 4; ++n) {
      const int ccol = col0 + wn * 64 + n * 16 + lrow;
#pragma unroll
      for (int r = 0; r < 4; ++r) {
        const int rrow = row0 + wm * 64 + m * 16 + lhi * 4 + r;
        xg[(size_t)rrow * G_ + ccol] = (_Float16)acc[m][n][r];
      }
    }
}

// ---- Phase R: persistent MFMA recurrent kernel (champion) ----
__global__ __launch_bounds__(RTHR) void lstm_mfma(
    const _Float16* __restrict__ Wt, const _Float16* __restrict__ xg,
    unsigned short* hring, float* cbuf, unsigned* flg,
    float* out, int t0, int nt)
{
  __shared__ float red[8 * 32 * 17];   // [wave][b][c] stride-17

  const int wg = blockIdx.x;
  const int tid = threadIdx.x;
  const int J0 = 4 * ((wg & 7) * 32 + (wg >> 3));   // XCD-contiguous hidden blocks

  const int wave = tid >> 6;
  const int lane = tid & 63;
  const int lrow = lane & 15;
  const int lhi  = lane >> 4;
  const int Kw   = wave * 128;
  const int gcol = (lrow >> 2) * H_ + J0 + (lrow & 3);

  f16x8 bf[4];
#pragma unroll
  for (int s = 0; s < 4; ++s)
    bf[s] = *(const f16x8*)(Wt + (size_t)gcol * H_ + Kw + s * 32 + lhi * 8);

  const int bq = tid >> 2, jq = tid & 3;   // epilogue mapping (tid<128)
  float cstate = 0.f;
  if (tid < 128) cstate = cbuf[(size_t)bq * H_ + J0 + jq];

  float xv0 = 0.f, xv1 = 0.f, xv2 = 0.f, xv3 = 0.f;
  if (tid < 128) {
    const _Float16* xp = xg + (size_t)bq * G_ + J0 + jq;
    xv0 = (float)xp[0];      xv1 = (float)xp[H_];
    xv2 = (float)xp[2 * H_]; xv3 = (float)xp[3 * H_];
  }

  for (int t = t0; t < t0 + nt; ++t) {
    const int lt = t - t0;
    const _Float16* hrd = (const _Float16*)hring + (size_t)lt * BH_;   // first touch
    unsigned short* hwr = hring + (size_t)((lt == nt - 1) ? 0 : lt + 1) * BH_;

    // ---- gate: wave 0 polls all 256 flags for step t (4 per lane) ----
    if (wave == 0) {
      const unsigned* fp = flg + (size_t)t * 256 + lane * 4;
      int guard = 0;
      for (;;) {
        unsigned a0 = __hip_atomic_load(fp + 0, __ATOMIC_RELAXED, __HIP_MEMORY_SCOPE_AGENT);
        unsigned a1 = __hip_atomic_load(fp + 1, __ATOMIC_RELAXED, __HIP_MEMORY_SCOPE_AGENT);
        unsigned a2 = __hip_atomic_load(fp + 2, __ATOMIC_RELAXED, __HIP_MEMORY_SCOPE_AGENT);
        unsigned a3 = __hip_atomic_load(fp + 3, __ATOMIC_RELAXED, __HIP_MEMORY_SCOPE_AGENT);
        if (__all((a0 & a1 & a2 & a3) != 0u)) break;
        __builtin_amdgcn_s_sleep(1);
        if (++guard > (1 << 22)) break;   // bounded: fail loud, never hang
      }
    }
    __syncthreads();   // A: h[t] visible (flags observed)

    f32x4 acc0 = {0.f, 0.f, 0.f, 0.f};
    f32x4 acc1 = {0.f, 0.f, 0.f, 0.f};
#pragma unroll
    for (int s = 0; s < 4; ++s) {
      f16x8 a0 = *(const f16x8*)(hrd + (size_t)lrow * H_ + Kw + s * 32 + lhi * 8);
      f16x8 a1 = *(const f16x8*)(hrd + (size_t)(16 + lrow) * H_ + Kw + s * 32 + lhi * 8);
      acc0 = __builtin_amdgcn_mfma_f32_16x16x32_f16(a0, bf[s], acc0, 0, 0, 0);
      acc1 = __builtin_amdgcn_mfma_f32_16x16x32_f16(a1, bf[s], acc1, 0, 0, 0);
    }

    // next-step xg prefetch (hidden under reduce+store+sync)
    float xn0 = 0.f, xn1 = 0.f, xn2 = 0.f, xn3 = 0.f;
    if (tid < 128) {
      const int nlt = (lt == nt - 1) ? lt : lt + 1;
      const _Float16* xp = xg + ((size_t)nlt * B_ + bq) * G_ + J0 + jq;
      xn0 = (float)xp[0];      xn1 = (float)xp[H_];
      xn2 = (float)xp[2 * H_]; xn3 = (float)xp[3 * H_];
    }

#pragma unroll
    for (int r = 0; r < 4; ++r) {
      red[(wave * 32 + lhi * 4 + r) * 17 + lrow]      = acc0[r];
      red[(wave * 32 + 16 + lhi * 4 + r) * 17 + lrow] = acc1[r];
    }
    __syncthreads();   // B

    if (tid < 128) {
      float g0 = xv0, g1 = xv1, g2 = xv2, g3 = xv3;
#pragma unroll
      for (int w = 0; w < 8; ++w) {
        const float* rp = red + (w * 32 + bq) * 17;
        g0 += rp[jq];
        g1 += rp[4 + jq];
        g2 += rp[8 + jq];
        g3 += rp[12 + jq];
      }
      float ig = sigmoidf_(g0);
      float fg = sigmoidf_(g1);
      float gg = tanhf_(g2);
      float og = sigmoidf_(g3);
      cstate = fg * cstate + ig * gg;
      float hval = og * tanhf_(cstate);
      out[((size_t)bq * S_ + t) * H_ + J0 + jq] = hval;   // f32, pre-quantization
      _Float16 hf = (_Float16)hval;
      unsigned short hb;
      __builtin_memcpy(&hb, &hf, 2);
      __hip_atomic_store(hwr + (size_t)bq * H_ + J0 + jq, hb,
                         __ATOMIC_RELAXED, __HIP_MEMORY_SCOPE_AGENT);
    }
    __syncthreads();   // C: all h stores acked at MALL (vmcnt drained per wave)

    if (tid == 0)      // publish: single write-through flag store, no ack wait
      __hip_atomic_store(flg + (size_t)(t + 1) * 256 + wg, 1u,
                         __ATOMIC_RELAXED, __HIP_MEMORY_SCOPE_AGENT);

    xv0 = xn0; xv1 = xn1; xv2 = xn2; xv3 = xn3;
  }

  if (tid < 128) cbuf[(size_t)bq * H_ + J0 + jq] = cstate;
}

// ---------------- host ----------------
extern "C" void kernel_launch(void* const* d_in, const int* in_sizes, int n_in,
                              void* d_out, int out_size, void* d_ws, size_t ws_size,
                              hipStream_t stream) {
  const int*   src = (const int*)d_in[0];
  const float* emb = (const float*)d_in[1];
  const float* Wih = (const float*)d_in[2];
  const float* Whh = (const float*)d_in[3];
  const float* bih = (const float*)d_in[4];
  const float* bhh = (const float*)d_in[5];
  float* out = (float*)d_out;

  // ws: [cbuf 128K][flg (S+1)*256*4][Wt 8M][Wt2 4M][hring][Af16][xg f16]
  char* ws = (char*)d_ws;
  float*    cbuf = (float*)ws;                          // 131072
  unsigned* flg  = (unsigned*)(ws + 131072);            // 513*256*4 = 525312
  const size_t stateBytes = 131072 + 525312;            // 656384
  _Float16* Wt  = (_Float16*)(ws + stateBytes);                    // 8 MB
  _Float16* Wt2 = (_Float16*)(ws + stateBytes + 8388608);          // 4 MB
  const size_t fixedBytes = stateBytes + 8388608 + 4194304;

  int chunk = 0;
  const int cand[4] = {512, 256, 128, 64};
  for (int ci = 0; ci < 4; ++ci) {
    size_t need = fixedBytes + (size_t)(cand[ci] + 1) * (BH_ * 2)   // hring
                  + (size_t)cand[ci] * B_ * E_ * 2                  // Af16
                  + (size_t)cand[ci] * B_ * G_ * 2;                 // xg f16
    if (need <= ws_size) { chunk = cand[ci]; break; }
  }
  if (chunk == 0) return;  // fail loud

  unsigned short* hring = (unsigned short*)(ws + fixedBytes);
  _Float16* Af16 = (_Float16*)(ws + fixedBytes + (size_t)(chunk + 1) * (BH_ * 2));
  _Float16* xg   = (_Float16*)(ws + fixedBytes + (size_t)(chunk + 1) * (BH_ * 2)
                               + (size_t)chunk * B_ * E_ * 2);

  (void)hipMemsetAsync(ws, 0, stateBytes, stream);   // c0 = 0, all flags = 0
  (void)hipMemsetAsync(flg, 1, 1024, stream);        // flags[t=0][0..255] nonzero
  (void)hipMemsetAsync(hring, 0, BH_ * 2, stream);   // h0 = 0 (ring slot 0)

  int K1 = H_, K2 = E_;
  wt_kernel<<<dim3(64, 16), 256, 0, stream>>>(Whh, Wt, K1);
  wt_kernel<<<dim3(64, 8), 256, 0, stream>>>(Wih, Wt2, K2);

  for (int t0 = 0; t0 < S_; t0 += chunk) {
    gather_a<<<dim3(chunk * B_), 128, 0, stream>>>(src, emb, Af16, t0);
    xgates_mfma<<<dim3(G_ / 128, chunk * B_ / 128), 256, 0, stream>>>(
        Af16, Wt2, bih, bhh, xg);

    int nt = chunk;
    void* args[] = {(void*)&Wt, (void*)&xg, (void*)&hring, (void*)&cbuf,
                    (void*)&flg, (void*)&out, (void*)&t0, (void*)&nt};
    (void)hipLaunchCooperativeKernel((void*)lstm_mfma, dim3(NWG), dim3(RTHR),
                                     args, 0u, stream);
  }
}